// Round 1
// baseline (2636.764 us; speedup 1.0000x reference)
//
#include <hip/hip_runtime.h>
#include <math.h>

#define N_U 100000
#define N_V 100000
#define D 128
#define E1 3200000
#define E2 3200000
#define ETOT (E1 + E2)

// ---------------------------------------------------------------------------
// Kernel 1: H = X @ W   (X: nrows x 128, W: 128 x 128)  fp32 VALU GEMM.
// W (64KB) fully in LDS, 32 rows of X per block, 8 rows x 2 cols per thread.
// ---------------------------------------------------------------------------
#define LNT 32
__global__ __launch_bounds__(256) void linear_kernel(
    const float* __restrict__ X, const float* __restrict__ W,
    float* __restrict__ H, int nrows) {
  __shared__ float Ws[D * D];     // 64 KB
  __shared__ float Xs[LNT * D];   // 16 KB
  const int t = threadIdx.x;

  for (int i = t * 4; i < D * D; i += 256 * 4)
    *(float4*)&Ws[i] = *(const float4*)&W[i];

  const int row0 = blockIdx.x * LNT;  // grid sized exactly: nrows % 32 == 0
  for (int i = t * 4; i < LNT * D; i += 256 * 4)
    *(float4*)&Xs[i] = *(const float4*)&X[(size_t)row0 * D + i];
  __syncthreads();

  const int tx = t & 63;   // col j = tx, tx+64
  const int ty = t >> 6;   // rows ty*8 .. ty*8+7
  float acc[8][2];
#pragma unroll
  for (int r = 0; r < 8; r++) { acc[r][0] = 0.f; acc[r][1] = 0.f; }

#pragma unroll 4
  for (int k = 0; k < D; k++) {
    float w0 = Ws[k * D + tx];
    float w1 = Ws[k * D + tx + 64];
#pragma unroll
    for (int r = 0; r < 8; r++) {
      float xv = Xs[(ty * 8 + r) * D + k];
      acc[r][0] = fmaf(xv, w0, acc[r][0]);
      acc[r][1] = fmaf(xv, w1, acc[r][1]);
    }
  }
#pragma unroll
  for (int r = 0; r < 8; r++) {
    size_t o = (size_t)(row0 + ty * 8 + r) * D;
    H[o + tx] = acc[r][0];
    H[o + tx + 64] = acc[r][1];
  }
}

// ---------------------------------------------------------------------------
// CSR build: count -> scan -> fill
// ---------------------------------------------------------------------------
__global__ void count_kernel(const int* __restrict__ e1,
                             const int* __restrict__ e2, int* __restrict__ deg) {
  for (int i = blockIdx.x * blockDim.x + threadIdx.x; i < ETOT;
       i += gridDim.x * blockDim.x) {
    int dst = (i < E1) ? e1[E1 + i] : e2[E2 + (i - E1)];
    atomicAdd(&deg[dst], 1);
  }
}

#define SCAN_TILE 2048
#define SCAN_NTILES ((N_V + SCAN_TILE - 1) / SCAN_TILE)  // 49

__global__ void scan_reduce(const int* __restrict__ deg, int* __restrict__ tileSums) {
  __shared__ int s[256];
  int base = blockIdx.x * SCAN_TILE + threadIdx.x * 8;
  int v = 0;
#pragma unroll
  for (int i = 0; i < 8; i++) {
    int idx = base + i;
    if (idx < N_V) v += deg[idx];
  }
  s[threadIdx.x] = v;
  __syncthreads();
  for (int off = 128; off > 0; off >>= 1) {
    if (threadIdx.x < off) s[threadIdx.x] += s[threadIdx.x + off];
    __syncthreads();
  }
  if (threadIdx.x == 0) tileSums[blockIdx.x] = s[0];
}

__global__ void scan_tiles(int* __restrict__ tileSums, int n) {
  if (threadIdx.x == 0 && blockIdx.x == 0) {
    int acc = 0;
    for (int i = 0; i < n; i++) { int v = tileSums[i]; tileSums[i] = acc; acc += v; }
  }
}

__global__ void scan_final(const int* __restrict__ deg,
                           const int* __restrict__ tileSums,
                           int* __restrict__ row_ptr, int* __restrict__ cursor) {
  __shared__ int s[256];
  const int t = threadIdx.x;
  int base = blockIdx.x * SCAN_TILE + t * 8;
  int vals[8];
  int acc = 0;
#pragma unroll
  for (int i = 0; i < 8; i++) {
    int idx = base + i;
    int v = (idx < N_V) ? deg[idx] : 0;
    vals[i] = acc;
    acc += v;
  }
  s[t] = acc;
  __syncthreads();
  for (int off = 1; off < 256; off <<= 1) {
    int v = (t >= off) ? s[t - off] : 0;
    __syncthreads();
    s[t] += v;
    __syncthreads();
  }
  int toff = tileSums[blockIdx.x] + s[t] - acc;  // exclusive offset for this thread
#pragma unroll
  for (int i = 0; i < 8; i++) {
    int idx = base + i;
    if (idx < N_V) {
      int p = toff + vals[i];
      row_ptr[idx] = p;
      cursor[idx] = p;
    }
  }
  if (blockIdx.x == 0 && t == 0) row_ptr[N_V] = ETOT;
}

__global__ void fill_kernel(const int* __restrict__ e1, const int* __restrict__ e2,
                            int* __restrict__ cursor, int* __restrict__ col) {
  for (int i = blockIdx.x * blockDim.x + threadIdx.x; i < ETOT;
       i += gridDim.x * blockDim.x) {
    int dst, enc;
    if (i < E1) {            // r1: src indexes x_u -> h_u stored at offset N_V
      dst = e1[E1 + i];
      enc = N_V + e1[i];
    } else {
      int j = i - E1;        // r2: src indexes x_v -> h_v at offset 0
      dst = e2[E2 + j];
      enc = e2[j];
    }
    int p = atomicAdd(&cursor[dst], 1);
    col[p] = enc;
  }
}

// ---------------------------------------------------------------------------
// Aggregation: one wave per dst node; lane l holds features 2l,2l+1.
// sum and max(.,0) in registers, single write per node.
// ---------------------------------------------------------------------------
__global__ __launch_bounds__(256) void aggregate_kernel(
    const float* __restrict__ H, const int* __restrict__ row_ptr,
    const int* __restrict__ col, float* __restrict__ Sum, float* __restrict__ Mx) {
  const int node = blockIdx.x * 4 + (threadIdx.x >> 6);
  const int lane = threadIdx.x & 63;
  const int start = row_ptr[node];
  const int end = row_ptr[node + 1];

  float sx = 0.f, sy = 0.f;
  float mx = 0.f, my = 0.f;  // floor at 0 == final max(segment_max, 0)

  int i = start;
  for (; i + 3 < end; i += 4) {
    int c0 = col[i], c1 = col[i + 1], c2 = col[i + 2], c3 = col[i + 3];
    float2 v0 = *(const float2*)&H[(size_t)c0 * D + lane * 2];
    float2 v1 = *(const float2*)&H[(size_t)c1 * D + lane * 2];
    float2 v2 = *(const float2*)&H[(size_t)c2 * D + lane * 2];
    float2 v3 = *(const float2*)&H[(size_t)c3 * D + lane * 2];
    sx += v0.x; sy += v0.y; mx = fmaxf(mx, v0.x); my = fmaxf(my, v0.y);
    sx += v1.x; sy += v1.y; mx = fmaxf(mx, v1.x); my = fmaxf(my, v1.y);
    sx += v2.x; sy += v2.y; mx = fmaxf(mx, v2.x); my = fmaxf(my, v2.y);
    sx += v3.x; sy += v3.y; mx = fmaxf(mx, v3.x); my = fmaxf(my, v3.y);
  }
  for (; i < end; i++) {
    int c0 = col[i];
    float2 v0 = *(const float2*)&H[(size_t)c0 * D + lane * 2];
    sx += v0.x; sy += v0.y; mx = fmaxf(mx, v0.x); my = fmaxf(my, v0.y);
  }
  size_t o = (size_t)node * D + lane * 2;
  float2 s2; s2.x = sx; s2.y = sy;
  float2 m2; m2.x = mx; m2.y = my;
  *(float2*)&Sum[o] = s2;
  *(float2*)&Mx[o] = m2;
}

// ---------------------------------------------------------------------------
// Epilogue: per 16-node tile: total=[s, s/cnt, mx] (384), gate=sigmoid(total@Wg+bg),
// out = (total*gate)@Wa + ba, masked where abssum(total)==0.
// ---------------------------------------------------------------------------
#define ENT 16
__global__ __launch_bounds__(256) void epilogue_kernel(
    const float* __restrict__ Sum, const float* __restrict__ Mx,
    const int* __restrict__ row_ptr, const float* __restrict__ Wg,
    const float* __restrict__ bg, const float* __restrict__ Wa,
    const float* __restrict__ ba, float* __restrict__ Out) {
  __shared__ float T[ENT][384];    // 24 KB
  __shared__ float TG[ENT][384];   // 24 KB
  __shared__ float Wp[16 * 384];   // 24 KB (reused as 32x128 in GEMM2)
  __shared__ float absr[ENT];

  const int t = threadIdx.x;
  const int node0 = blockIdx.x * ENT;  // 100000/16 = 6250 exact

  // stage total tile
  for (int i = t; i < ENT * 128; i += 256) {
    int n = i >> 7, j = i & 127;
    int nd = node0 + n;
    float sv = Sum[(size_t)nd * D + j];
    int cnt = row_ptr[nd + 1] - row_ptr[nd];
    float inv = 1.0f / (float)(cnt > 0 ? cnt : 1);
    T[n][j] = sv;
    T[n][128 + j] = sv * inv;
    T[n][256 + j] = Mx[(size_t)nd * D + j];
  }
  __syncthreads();

  if (t < ENT) {
    float a = 0.f;
    for (int k = 0; k < 384; k++) a += fabsf(T[t][k]);
    absr[t] = a;
  }

  const int tx = t & 63;
  const int ty = t >> 6;

  // ---- GEMM1: G = sigmoid(T @ Wg + bg); TG = T * G ----
  float acc[4][6];
#pragma unroll
  for (int r = 0; r < 4; r++)
#pragma unroll
    for (int c = 0; c < 6; c++) acc[r][c] = bg[tx + 64 * c];

  for (int k0 = 0; k0 < 384; k0 += 16) {
    __syncthreads();  // protect previous panel (and absr on first iter)
    for (int i = t * 4; i < 16 * 384; i += 1024)
      *(float4*)&Wp[i] = *(const float4*)&Wg[(size_t)k0 * 384 + i];
    __syncthreads();
#pragma unroll
    for (int kk = 0; kk < 16; kk++) {
      float w[6];
#pragma unroll
      for (int c = 0; c < 6; c++) w[c] = Wp[kk * 384 + tx + 64 * c];
#pragma unroll
      for (int r = 0; r < 4; r++) {
        float tv = T[ty * 4 + r][k0 + kk];
#pragma unroll
        for (int c = 0; c < 6; c++) acc[r][c] = fmaf(tv, w[c], acc[r][c]);
      }
    }
  }
#pragma unroll
  for (int r = 0; r < 4; r++) {
    int n = ty * 4 + r;
#pragma unroll
    for (int c = 0; c < 6; c++) {
      int j = tx + 64 * c;
      float g = 1.0f / (1.0f + expf(-acc[r][c]));
      TG[n][j] = T[n][j] * g;
    }
  }
  __syncthreads();

  // ---- GEMM2: out = TG @ Wa + ba ----
  float acc2[4][2];
#pragma unroll
  for (int r = 0; r < 4; r++) {
    acc2[r][0] = ba[tx];
    acc2[r][1] = ba[tx + 64];
  }
  for (int k0 = 0; k0 < 384; k0 += 32) {
    __syncthreads();
    for (int i = t * 4; i < 32 * 128; i += 1024)
      *(float4*)&Wp[i] = *(const float4*)&Wa[(size_t)k0 * 128 + i];
    __syncthreads();
#pragma unroll
    for (int kk = 0; kk < 32; kk++) {
      float w0 = Wp[kk * 128 + tx];
      float w1 = Wp[kk * 128 + tx + 64];
#pragma unroll
      for (int r = 0; r < 4; r++) {
        float tv = TG[ty * 4 + r][k0 + kk];
        acc2[r][0] = fmaf(tv, w0, acc2[r][0]);
        acc2[r][1] = fmaf(tv, w1, acc2[r][1]);
      }
    }
  }
#pragma unroll
  for (int r = 0; r < 4; r++) {
    int n = ty * 4 + r;
    float msk = (absr[n] == 0.f) ? 0.f : 1.f;
    size_t o = (size_t)(node0 + n) * D;
    Out[o + tx] = acc2[r][0] * msk;
    Out[o + tx + 64] = acc2[r][1] * msk;
  }
}

// ---------------------------------------------------------------------------
extern "C" void kernel_launch(void* const* d_in, const int* in_sizes, int n_in,
                              void* d_out, int out_size, void* d_ws, size_t ws_size,
                              hipStream_t stream) {
  const float* x_u = (const float*)d_in[0];
  const float* x_v = (const float*)d_in[1];
  const float* W_r1 = (const float*)d_in[2];
  const float* W_r2 = (const float*)d_in[3];
  const float* W_gate = (const float*)d_in[4];
  const float* b_gate = (const float*)d_in[5];
  const float* W_aggr = (const float*)d_in[6];
  const float* b_aggr = (const float*)d_in[7];
  const int* e1 = (const int*)d_in[8];
  const int* e2 = (const int*)d_in[9];
  float* out = (float*)d_out;

  char* ws = (char*)d_ws;
  size_t off = 0;
  float* h = (float*)(ws + off);      off += (size_t)(N_V + N_U) * D * 4;  // 102.4 MB
  float* Sum = (float*)(ws + off);    off += (size_t)N_V * D * 4;          // 51.2 MB
  float* Mx = (float*)(ws + off);     off += (size_t)N_V * D * 4;          // 51.2 MB
  int* colA = (int*)(ws + off);       off += (size_t)ETOT * 4;             // 25.6 MB
  int* row_ptr = (int*)(ws + off);    off += (size_t)(N_V + 1) * 4;
  int* cursor = (int*)(ws + off);     off += (size_t)N_V * 4;
  int* deg = (int*)(ws + off);        off += (size_t)N_V * 4;
  int* tileSums = (int*)(ws + off);   off += 64 * 4;

  hipMemsetAsync(deg, 0, (size_t)N_V * 4, stream);

  // h_v = x_v @ W_r2 at offset 0; h_u = x_u @ W_r1 at offset N_V*D
  linear_kernel<<<N_V / LNT, 256, 0, stream>>>(x_v, W_r2, h, N_V);
  linear_kernel<<<N_U / LNT, 256, 0, stream>>>(x_u, W_r1, h + (size_t)N_V * D, N_U);

  count_kernel<<<2048, 256, 0, stream>>>(e1, e2, deg);
  scan_reduce<<<SCAN_NTILES, 256, 0, stream>>>(deg, tileSums);
  scan_tiles<<<1, 64, 0, stream>>>(tileSums, SCAN_NTILES);
  scan_final<<<SCAN_NTILES, 256, 0, stream>>>(deg, tileSums, row_ptr, cursor);
  fill_kernel<<<2048, 256, 0, stream>>>(e1, e2, cursor, colA);

  aggregate_kernel<<<N_V / 4, 256, 0, stream>>>(h, row_ptr, colA, Sum, Mx);

  epilogue_kernel<<<N_V / ENT, 256, 0, stream>>>(Sum, Mx, row_ptr, W_gate, b_gate,
                                                 W_aggr, b_aggr, out);
}

// Round 2
// 1906.634 us; speedup vs baseline: 1.3829x; 1.3829x over previous
//
#include <hip/hip_runtime.h>
#include <math.h>

#define N_U 100000
#define N_V 100000
#define D 128
#define E1 3200000
#define E2 3200000
#define ETOT (E1 + E2)

typedef __bf16 bf16x8 __attribute__((ext_vector_type(8)));
typedef float f32x4 __attribute__((ext_vector_type(4)));

__device__ __forceinline__ unsigned short f2b(float f) {
  union { float f; unsigned int u; } v; v.f = f;
  unsigned int u = v.u;
  unsigned int r = u + 0x7fffu + ((u >> 16) & 1u);
  return (unsigned short)(r >> 16);
}
__device__ __forceinline__ float b2f(unsigned short s) {
  union { unsigned int u; float f; } v; v.u = ((unsigned int)s) << 16; return v.f;
}

// ---------------------------------------------------------------------------
// Kernel 1: H = X @ W   (X: nrows x 128, W: 128 x 128)  fp32 VALU GEMM.
// ---------------------------------------------------------------------------
#define LNT 32
__global__ __launch_bounds__(256) void linear_kernel(
    const float* __restrict__ X, const float* __restrict__ W,
    float* __restrict__ H, int nrows) {
  __shared__ float Ws[D * D];     // 64 KB
  __shared__ float Xs[LNT * D];   // 16 KB
  const int t = threadIdx.x;

  for (int i = t * 4; i < D * D; i += 256 * 4)
    *(float4*)&Ws[i] = *(const float4*)&W[i];

  const int row0 = blockIdx.x * LNT;
  for (int i = t * 4; i < LNT * D; i += 256 * 4)
    *(float4*)&Xs[i] = *(const float4*)&X[(size_t)row0 * D + i];
  __syncthreads();

  const int tx = t & 63;
  const int ty = t >> 6;
  float acc[8][2];
#pragma unroll
  for (int r = 0; r < 8; r++) { acc[r][0] = 0.f; acc[r][1] = 0.f; }

#pragma unroll 4
  for (int k = 0; k < D; k++) {
    float w0 = Ws[k * D + tx];
    float w1 = Ws[k * D + tx + 64];
#pragma unroll
    for (int r = 0; r < 8; r++) {
      float xv = Xs[(ty * 8 + r) * D + k];
      acc[r][0] = fmaf(xv, w0, acc[r][0]);
      acc[r][1] = fmaf(xv, w1, acc[r][1]);
    }
  }
#pragma unroll
  for (int r = 0; r < 8; r++) {
    size_t o = (size_t)(row0 + ty * 8 + r) * D;
    H[o + tx] = acc[r][0];
    H[o + tx + 64] = acc[r][1];
  }
}

// ---------------------------------------------------------------------------
// CSR build: count -> scan -> fill
// ---------------------------------------------------------------------------
__global__ void count_kernel(const int* __restrict__ e1,
                             const int* __restrict__ e2, int* __restrict__ deg) {
  for (int i = blockIdx.x * blockDim.x + threadIdx.x; i < ETOT;
       i += gridDim.x * blockDim.x) {
    int dst = (i < E1) ? e1[E1 + i] : e2[E2 + (i - E1)];
    atomicAdd(&deg[dst], 1);
  }
}

#define SCAN_TILE 2048
#define SCAN_NTILES ((N_V + SCAN_TILE - 1) / SCAN_TILE)  // 49

__global__ void scan_reduce(const int* __restrict__ deg, int* __restrict__ tileSums) {
  __shared__ int s[256];
  int base = blockIdx.x * SCAN_TILE + threadIdx.x * 8;
  int v = 0;
#pragma unroll
  for (int i = 0; i < 8; i++) {
    int idx = base + i;
    if (idx < N_V) v += deg[idx];
  }
  s[threadIdx.x] = v;
  __syncthreads();
  for (int off = 128; off > 0; off >>= 1) {
    if (threadIdx.x < off) s[threadIdx.x] += s[threadIdx.x + off];
    __syncthreads();
  }
  if (threadIdx.x == 0) tileSums[blockIdx.x] = s[0];
}

__global__ void scan_tiles(int* __restrict__ tileSums, int n) {
  if (threadIdx.x == 0 && blockIdx.x == 0) {
    int acc = 0;
    for (int i = 0; i < n; i++) { int v = tileSums[i]; tileSums[i] = acc; acc += v; }
  }
}

__global__ void scan_final(const int* __restrict__ deg,
                           const int* __restrict__ tileSums,
                           int* __restrict__ row_ptr, int* __restrict__ cursor) {
  __shared__ int s[256];
  const int t = threadIdx.x;
  int base = blockIdx.x * SCAN_TILE + t * 8;
  int vals[8];
  int acc = 0;
#pragma unroll
  for (int i = 0; i < 8; i++) {
    int idx = base + i;
    int v = (idx < N_V) ? deg[idx] : 0;
    vals[i] = acc;
    acc += v;
  }
  s[t] = acc;
  __syncthreads();
  for (int off = 1; off < 256; off <<= 1) {
    int v = (t >= off) ? s[t - off] : 0;
    __syncthreads();
    s[t] += v;
    __syncthreads();
  }
  int toff = tileSums[blockIdx.x] + s[t] - acc;
#pragma unroll
  for (int i = 0; i < 8; i++) {
    int idx = base + i;
    if (idx < N_V) {
      int p = toff + vals[i];
      row_ptr[idx] = p;
      cursor[idx] = p;
    }
  }
  if (blockIdx.x == 0 && t == 0) row_ptr[N_V] = ETOT;
}

__global__ void fill_kernel(const int* __restrict__ e1, const int* __restrict__ e2,
                            int* __restrict__ cursor, int* __restrict__ col) {
  for (int i = blockIdx.x * blockDim.x + threadIdx.x; i < ETOT;
       i += gridDim.x * blockDim.x) {
    int dst, enc;
    if (i < E1) {
      dst = e1[E1 + i];
      enc = N_V + e1[i];
    } else {
      int j = i - E1;
      dst = e2[E2 + j];
      enc = e2[j];
    }
    int p = atomicAdd(&cursor[dst], 1);
    col[p] = enc;
  }
}

// ---------------------------------------------------------------------------
// Aggregation: one wave per dst node; lane l holds features 2l,2l+1.
// ---------------------------------------------------------------------------
__global__ __launch_bounds__(256) void aggregate_kernel(
    const float* __restrict__ H, const int* __restrict__ row_ptr,
    const int* __restrict__ col, float* __restrict__ Sum, float* __restrict__ Mx) {
  const int node = blockIdx.x * 4 + (threadIdx.x >> 6);
  const int lane = threadIdx.x & 63;
  const int start = row_ptr[node];
  const int end = row_ptr[node + 1];

  float sx = 0.f, sy = 0.f;
  float mx = 0.f, my = 0.f;

  int i = start;
  for (; i + 3 < end; i += 4) {
    int c0 = col[i], c1 = col[i + 1], c2 = col[i + 2], c3 = col[i + 3];
    float2 v0 = *(const float2*)&H[(size_t)c0 * D + lane * 2];
    float2 v1 = *(const float2*)&H[(size_t)c1 * D + lane * 2];
    float2 v2 = *(const float2*)&H[(size_t)c2 * D + lane * 2];
    float2 v3 = *(const float2*)&H[(size_t)c3 * D + lane * 2];
    sx += v0.x; sy += v0.y; mx = fmaxf(mx, v0.x); my = fmaxf(my, v0.y);
    sx += v1.x; sy += v1.y; mx = fmaxf(mx, v1.x); my = fmaxf(my, v1.y);
    sx += v2.x; sy += v2.y; mx = fmaxf(mx, v2.x); my = fmaxf(my, v2.y);
    sx += v3.x; sy += v3.y; mx = fmaxf(mx, v3.x); my = fmaxf(my, v3.y);
  }
  for (; i < end; i++) {
    int c0 = col[i];
    float2 v0 = *(const float2*)&H[(size_t)c0 * D + lane * 2];
    sx += v0.x; sy += v0.y; mx = fmaxf(mx, v0.x); my = fmaxf(my, v0.y);
  }
  size_t o = (size_t)node * D + lane * 2;
  float2 s2; s2.x = sx; s2.y = sy;
  float2 m2; m2.x = mx; m2.y = my;
  *(float2*)&Sum[o] = s2;
  *(float2*)&Mx[o] = m2;
}

// ---------------------------------------------------------------------------
// Weight conversion: WgT[n][k] = bf16(Wg[k][n]) (384x384), WaT[n][k] (128x384)
// ---------------------------------------------------------------------------
__global__ void convert_wg(const float* __restrict__ Wg, unsigned short* __restrict__ WgT) {
  int idx = blockIdx.x * 256 + threadIdx.x;
  if (idx < 384 * 384) {
    int n = idx / 384, k = idx - n * 384;
    WgT[idx] = f2b(Wg[k * 384 + n]);
  }
}
__global__ void convert_wa(const float* __restrict__ Wa, unsigned short* __restrict__ WaT) {
  int idx = blockIdx.x * 256 + threadIdx.x;
  if (idx < 128 * 384) {
    int n = idx / 384, k = idx - n * 384;
    WaT[idx] = f2b(Wa[k * 128 + n]);
  }
}

// ---------------------------------------------------------------------------
// MFMA epilogue: 64 nodes/block, 4 waves, wave w owns rows 16w..16w+15.
// T = [s | s/cnt | mx] bf16 in LDS; GEMM1 (K=384,N=384) -> gate -> TG in-place;
// GEMM2 (K=384,N=128) -> +ba, mask, store fp32.
// A-layout: lane holds A[m=lane&15][k=(lane>>4)*8 + j]; B-frag symmetric
// (WgT/WaT stored n-major,k-contiguous). C/D: col=lane&15, row=(lane>>4)*4+r.
// ---------------------------------------------------------------------------
#define EM 64
__global__ __launch_bounds__(256, 3) void epilogue_mfma(
    const float* __restrict__ Sum, const float* __restrict__ Mx,
    const int* __restrict__ row_ptr, const unsigned short* __restrict__ Wg16,
    const float* __restrict__ bg, const unsigned short* __restrict__ Wa16,
    const float* __restrict__ ba, float* __restrict__ Out) {
  __shared__ unsigned short Ts[EM][392];  // 50176 B (pad 8 -> 16B-aligned rows)
  __shared__ float invs[EM];
  __shared__ int cnts[EM];

  const int t = threadIdx.x;
  const int node0 = blockIdx.x * EM;

  if (t < EM) {
    int nd = node0 + t;
    int c = 0;
    if (nd < N_V) c = row_ptr[nd + 1] - row_ptr[nd];
    cnts[t] = c;
    invs[t] = 1.0f / (float)(c > 0 ? c : 1);
  }
  __syncthreads();

  // stage T tile (zeros for out-of-range nodes)
  for (int i = t; i < EM * 128; i += 256) {
    int n = i >> 7, j = i & 127;
    int nd = node0 + n;
    float sv = 0.f, mv = 0.f;
    if (nd < N_V) {
      sv = Sum[(size_t)nd * D + j];
      mv = Mx[(size_t)nd * D + j];
    }
    Ts[n][j] = f2b(sv);
    Ts[n][128 + j] = f2b(sv * invs[n]);
    Ts[n][256 + j] = f2b(mv);
  }
  __syncthreads();
  // After this barrier all LDS traffic is wave-private (each wave touches only
  // its own 16 rows) -> no further barriers needed.

  const int wv = t >> 6;
  const int ln = t & 63;
  const int lr = ln & 15;   // A-row / B-col / C-col
  const int lq = ln >> 4;   // quad
  const int m0 = wv * 16;

  // ---- GEMM1: G = sigmoid(T @ Wg + bg); TG = T*G in-place ----
  bf16x8 a[12];
#pragma unroll
  for (int ks = 0; ks < 12; ks++)
    a[ks] = *(const bf16x8*)&Ts[m0 + lr][ks * 32 + lq * 8];

  for (int np = 0; np < 12; np++) {  // pairs of 16-wide n-tiles
    const int n0 = np * 32;
    f32x4 acc0 = {0.f, 0.f, 0.f, 0.f};
    f32x4 acc1 = {0.f, 0.f, 0.f, 0.f};
    const unsigned short* B0 = &Wg16[(size_t)(n0 + lr) * 384 + lq * 8];
    const unsigned short* B1 = B0 + 16 * 384;
#pragma unroll
    for (int ks = 0; ks < 12; ks++) {
      bf16x8 b0 = *(const bf16x8*)(B0 + ks * 32);
      bf16x8 b1 = *(const bf16x8*)(B1 + ks * 32);
      acc0 = __builtin_amdgcn_mfma_f32_16x16x32_bf16(a[ks], b0, acc0, 0, 0, 0);
      acc1 = __builtin_amdgcn_mfma_f32_16x16x32_bf16(a[ks], b1, acc1, 0, 0, 0);
    }
    float bg0 = bg[n0 + lr];
    float bg1 = bg[n0 + 16 + lr];
#pragma unroll
    for (int r = 0; r < 4; r++) {
      int m = m0 + lq * 4 + r;
      float g0 = 1.f / (1.f + __expf(-(acc0[r] + bg0)));
      float g1 = 1.f / (1.f + __expf(-(acc1[r] + bg1)));
      float t0 = b2f(Ts[m][n0 + lr]);
      float t1 = b2f(Ts[m][n0 + 16 + lr]);
      Ts[m][n0 + lr] = f2b(t0 * g0);
      Ts[m][n0 + 16 + lr] = f2b(t1 * g1);
    }
  }

  // ---- GEMM2: out = TG @ Wa + ba, masked ----
  bf16x8 a2[12];
#pragma unroll
  for (int ks = 0; ks < 12; ks++)
    a2[ks] = *(const bf16x8*)&Ts[m0 + lr][ks * 32 + lq * 8];

  for (int np = 0; np < 4; np++) {
    const int n0 = np * 32;
    f32x4 acc0 = {0.f, 0.f, 0.f, 0.f};
    f32x4 acc1 = {0.f, 0.f, 0.f, 0.f};
    const unsigned short* B0 = &Wa16[(size_t)(n0 + lr) * 384 + lq * 8];
    const unsigned short* B1 = B0 + 16 * 384;
#pragma unroll
    for (int ks = 0; ks < 12; ks++) {
      bf16x8 b0 = *(const bf16x8*)(B0 + ks * 32);
      bf16x8 b1 = *(const bf16x8*)(B1 + ks * 32);
      acc0 = __builtin_amdgcn_mfma_f32_16x16x32_bf16(a2[ks], b0, acc0, 0, 0, 0);
      acc1 = __builtin_amdgcn_mfma_f32_16x16x32_bf16(a2[ks], b1, acc1, 0, 0, 0);
    }
    float ba0 = ba[n0 + lr];
    float ba1 = ba[n0 + 16 + lr];
#pragma unroll
    for (int r = 0; r < 4; r++) {
      int m = m0 + lq * 4 + r;
      int nd = node0 + m;
      if (nd < N_V) {
        float msk = (cnts[m] > 0) ? 1.f : 0.f;
        size_t o = (size_t)nd * D;
        Out[o + n0 + lr] = (acc0[r] + ba0) * msk;
        Out[o + n0 + 16 + lr] = (acc1[r] + ba1) * msk;
      }
    }
  }
}

// ---------------------------------------------------------------------------
extern "C" void kernel_launch(void* const* d_in, const int* in_sizes, int n_in,
                              void* d_out, int out_size, void* d_ws, size_t ws_size,
                              hipStream_t stream) {
  const float* x_u = (const float*)d_in[0];
  const float* x_v = (const float*)d_in[1];
  const float* W_r1 = (const float*)d_in[2];
  const float* W_r2 = (const float*)d_in[3];
  const float* W_gate = (const float*)d_in[4];
  const float* b_gate = (const float*)d_in[5];
  const float* W_aggr = (const float*)d_in[6];
  const float* b_aggr = (const float*)d_in[7];
  const int* e1 = (const int*)d_in[8];
  const int* e2 = (const int*)d_in[9];
  float* out = (float*)d_out;

  char* ws = (char*)d_ws;
  size_t off = 0;
  float* h = (float*)(ws + off);      off += (size_t)(N_V + N_U) * D * 4;
  float* Sum = (float*)(ws + off);    off += (size_t)N_V * D * 4;
  float* Mx = (float*)(ws + off);     off += (size_t)N_V * D * 4;
  int* colA = (int*)(ws + off);       off += (size_t)ETOT * 4;
  int* row_ptr = (int*)(ws + off);    off += (size_t)(N_V + 1) * 4;
  int* cursor = (int*)(ws + off);     off += (size_t)N_V * 4;
  int* deg = (int*)(ws + off);        off += (size_t)N_V * 4;
  int* tileSums = (int*)(ws + off);   off += 64 * 4;
  unsigned short* Wg16 = (unsigned short*)(ws + off); off += (size_t)384 * 384 * 2;
  unsigned short* Wa16 = (unsigned short*)(ws + off); off += (size_t)128 * 384 * 2;

  hipMemsetAsync(deg, 0, (size_t)N_V * 4, stream);

  linear_kernel<<<N_V / LNT, 256, 0, stream>>>(x_v, W_r2, h, N_V);
  linear_kernel<<<N_U / LNT, 256, 0, stream>>>(x_u, W_r1, h + (size_t)N_V * D, N_U);

  convert_wg<<<(384 * 384 + 255) / 256, 256, 0, stream>>>(W_gate, Wg16);
  convert_wa<<<(128 * 384 + 255) / 256, 256, 0, stream>>>(W_aggr, Wa16);

  count_kernel<<<2048, 256, 0, stream>>>(e1, e2, deg);
  scan_reduce<<<SCAN_NTILES, 256, 0, stream>>>(deg, tileSums);
  scan_tiles<<<1, 64, 0, stream>>>(tileSums, SCAN_NTILES);
  scan_final<<<SCAN_NTILES, 256, 0, stream>>>(deg, tileSums, row_ptr, cursor);
  fill_kernel<<<2048, 256, 0, stream>>>(e1, e2, cursor, colA);

  aggregate_kernel<<<N_V / 4, 256, 0, stream>>>(h, row_ptr, colA, Sum, Mx);

  epilogue_mfma<<<(N_V + EM - 1) / EM, 256, 0, stream>>>(
      Sum, Mx, row_ptr, Wg16, b_gate, Wa16, b_aggr, out);
}

// Round 3
// 1264.331 us; speedup vs baseline: 2.0855x; 1.5080x over previous
//
#include <hip/hip_runtime.h>
#include <math.h>

#define N_U 100000
#define N_V 100000
#define D 128
#define E1 3200000
#define E2 3200000
#define ETOT (E1 + E2)

#define NBUCK 196      // buckets of 512 dst nodes: dst >> 9
#define PCHUNK 4096    // edges per partition block

typedef __bf16 bf16x8 __attribute__((ext_vector_type(8)));
typedef float f32x4 __attribute__((ext_vector_type(4)));

__device__ __forceinline__ unsigned short f2b(float f) {
  union { float f; unsigned int u; } v; v.f = f;
  unsigned int u = v.u;
  unsigned int r = u + 0x7fffu + ((u >> 16) & 1u);
  return (unsigned short)(r >> 16);
}
__device__ __forceinline__ float b2f(unsigned short s) {
  union { unsigned int u; float f; } v; v.u = ((unsigned int)s) << 16; return v.f;
}

// ---------------------------------------------------------------------------
// Kernel 1: H = X @ W   (X: nrows x 128, W: 128 x 128)  fp32 VALU GEMM.
// ---------------------------------------------------------------------------
#define LNT 32
__global__ __launch_bounds__(256) void linear_kernel(
    const float* __restrict__ X, const float* __restrict__ W,
    float* __restrict__ H, int nrows) {
  __shared__ float Ws[D * D];     // 64 KB
  __shared__ float Xs[LNT * D];   // 16 KB
  const int t = threadIdx.x;

  for (int i = t * 4; i < D * D; i += 256 * 4)
    *(float4*)&Ws[i] = *(const float4*)&W[i];

  const int row0 = blockIdx.x * LNT;
  for (int i = t * 4; i < LNT * D; i += 256 * 4)
    *(float4*)&Xs[i] = *(const float4*)&X[(size_t)row0 * D + i];
  __syncthreads();

  const int tx = t & 63;
  const int ty = t >> 6;
  float acc[8][2];
#pragma unroll
  for (int r = 0; r < 8; r++) { acc[r][0] = 0.f; acc[r][1] = 0.f; }

#pragma unroll 4
  for (int k = 0; k < D; k++) {
    float w0 = Ws[k * D + tx];
    float w1 = Ws[k * D + tx + 64];
#pragma unroll
    for (int r = 0; r < 8; r++) {
      float xv = Xs[(ty * 8 + r) * D + k];
      acc[r][0] = fmaf(xv, w0, acc[r][0]);
      acc[r][1] = fmaf(xv, w1, acc[r][1]);
    }
  }
#pragma unroll
  for (int r = 0; r < 8; r++) {
    size_t o = (size_t)(row0 + ty * 8 + r) * D;
    H[o + tx] = acc[r][0];
    H[o + tx + 64] = acc[r][1];
  }
}

// ---------------------------------------------------------------------------
// Bucketed CSR build: bucket_count -> bucket_scan -> partition -> bucket_fill
// ---------------------------------------------------------------------------
__global__ __launch_bounds__(256) void bucket_count(
    const int* __restrict__ e1, const int* __restrict__ e2,
    int* __restrict__ bucketCnt) {
  __shared__ int hist[NBUCK];
  for (int i = threadIdx.x; i < NBUCK; i += 256) hist[i] = 0;
  __syncthreads();
  for (long i = (long)blockIdx.x * blockDim.x + threadIdx.x; i < ETOT;
       i += (long)gridDim.x * blockDim.x) {
    int dst = (i < E1) ? e1[E1 + i] : e2[E2 + (i - E1)];
    atomicAdd(&hist[dst >> 9], 1);
  }
  __syncthreads();
  for (int i = threadIdx.x; i < NBUCK; i += 256)
    if (hist[i]) atomicAdd(&bucketCnt[i], hist[i]);
}

__global__ __launch_bounds__(256) void bucket_scan(
    const int* __restrict__ bucketCnt, int* __restrict__ bucketBase,
    int* __restrict__ bucketCursor) {
  __shared__ int s[256];
  const int t = threadIdx.x;
  int v = (t < NBUCK) ? bucketCnt[t] : 0;
  s[t] = v;
  __syncthreads();
  for (int off = 1; off < 256; off <<= 1) {
    int tmp = (t >= off) ? s[t - off] : 0;
    __syncthreads();
    s[t] += tmp;
    __syncthreads();
  }
  int excl = s[t] - v;
  if (t < NBUCK) { bucketBase[t] = excl; bucketCursor[t] = excl; }
  if (t == 0) bucketBase[NBUCK] = ETOT;
}

// Each block: 4096 edges -> LDS hist -> reserve bucket ranges -> LDS-stage
// bucket-ordered -> coalesced flush of (enc, dst) records.
__global__ __launch_bounds__(256) void partition_kernel(
    const int* __restrict__ e1, const int* __restrict__ e2,
    int* __restrict__ bucketCursor, uint2* __restrict__ recs) {
  __shared__ int hist[256];
  __shared__ int scan_s[256];
  __shared__ int lstart[256];
  __shared__ int gbase[NBUCK];
  __shared__ int lcur[NBUCK];
  __shared__ uint2 buf[PCHUNK];  // 32 KB

  const int t = threadIdx.x;
  const long base = (long)blockIdx.x * PCHUNK;
  const int n = (int)min((long)PCHUNK, (long)ETOT - base);

  hist[t] = 0;
  __syncthreads();

  uint2 myrec[PCHUNK / 256];
  int myb[PCHUNK / 256];
  int cnt = 0;
#pragma unroll
  for (int k = 0; k < PCHUNK / 256; k++) {
    int idx = t + k * 256;
    if (idx < n) {
      long i = base + idx;
      int enc, dst;
      if (i < E1) {
        dst = e1[E1 + i];
        enc = N_V + e1[i];
      } else {
        long j = i - E1;
        dst = e2[E2 + j];
        enc = e2[j];
      }
      myrec[cnt] = make_uint2((unsigned)enc, (unsigned)dst);
      int b = dst >> 9;
      myb[cnt] = b;
      atomicAdd(&hist[b], 1);
      cnt++;
    }
  }
  __syncthreads();

  int v = hist[t];
  scan_s[t] = v;
  __syncthreads();
  for (int off = 1; off < 256; off <<= 1) {
    int tmp = (t >= off) ? scan_s[t - off] : 0;
    __syncthreads();
    scan_s[t] += tmp;
    __syncthreads();
  }
  lstart[t] = scan_s[t] - v;
  if (t < NBUCK) {
    gbase[t] = atomicAdd(&bucketCursor[t], v);
    lcur[t] = scan_s[t] - v;
  }
  __syncthreads();

  for (int k = 0; k < cnt; k++) {
    int p = atomicAdd(&lcur[myb[k]], 1);
    buf[p] = myrec[k];
  }
  __syncthreads();

  for (int p = t; p < n; p += 256) {
    uint2 r = buf[p];
    int b = (int)(r.y >> 9);
    recs[(size_t)gbase[b] + (p - lstart[b])] = r;
  }
}

// One block per bucket: per-node LDS histogram + scan -> row_ptr, then
// L2-local scatter of col within the bucket's edge range.
__global__ __launch_bounds__(512) void bucket_fill(
    const uint2* __restrict__ recs, const int* __restrict__ bucketBase,
    int* __restrict__ row_ptr, int* __restrict__ col) {
  __shared__ int hist[512];
  __shared__ int s[512];
  __shared__ int cur[512];
  const int t = threadIdx.x;
  const int b = blockIdx.x;
  const int base = bucketBase[b];
  const int eend = bucketBase[b + 1];
  const int n0 = b << 9;

  hist[t] = 0;
  __syncthreads();
  for (int p = base + t; p < eend; p += 512)
    atomicAdd(&hist[recs[p].y - n0], 1);
  __syncthreads();

  int v = hist[t];
  s[t] = v;
  __syncthreads();
  for (int off = 1; off < 512; off <<= 1) {
    int tmp = (t >= off) ? s[t - off] : 0;
    __syncthreads();
    s[t] += tmp;
    __syncthreads();
  }
  int excl = s[t] - v;
  cur[t] = excl;
  int nd = n0 + t;
  if (nd < N_V) row_ptr[nd] = base + excl;
  if (b == 0 && t == 0) row_ptr[N_V] = ETOT;
  __syncthreads();

  for (int p = base + t; p < eend; p += 512) {
    uint2 r = recs[p];
    int q = atomicAdd(&cur[r.y - n0], 1);
    col[base + q] = r.x;
  }
}

// ---------------------------------------------------------------------------
// Aggregation: one wave per dst node; lane l holds features 2l,2l+1.
// ---------------------------------------------------------------------------
__global__ __launch_bounds__(256) void aggregate_kernel(
    const float* __restrict__ H, const int* __restrict__ row_ptr,
    const int* __restrict__ col, float* __restrict__ Sum, float* __restrict__ Mx) {
  const int node = blockIdx.x * 4 + (threadIdx.x >> 6);
  const int lane = threadIdx.x & 63;
  const int start = row_ptr[node];
  const int end = row_ptr[node + 1];

  float sx = 0.f, sy = 0.f;
  float mx = 0.f, my = 0.f;

  int i = start;
  for (; i + 3 < end; i += 4) {
    int c0 = col[i], c1 = col[i + 1], c2 = col[i + 2], c3 = col[i + 3];
    float2 v0 = *(const float2*)&H[(size_t)c0 * D + lane * 2];
    float2 v1 = *(const float2*)&H[(size_t)c1 * D + lane * 2];
    float2 v2 = *(const float2*)&H[(size_t)c2 * D + lane * 2];
    float2 v3 = *(const float2*)&H[(size_t)c3 * D + lane * 2];
    sx += v0.x; sy += v0.y; mx = fmaxf(mx, v0.x); my = fmaxf(my, v0.y);
    sx += v1.x; sy += v1.y; mx = fmaxf(mx, v1.x); my = fmaxf(my, v1.y);
    sx += v2.x; sy += v2.y; mx = fmaxf(mx, v2.x); my = fmaxf(my, v2.y);
    sx += v3.x; sy += v3.y; mx = fmaxf(mx, v3.x); my = fmaxf(my, v3.y);
  }
  for (; i < end; i++) {
    int c0 = col[i];
    float2 v0 = *(const float2*)&H[(size_t)c0 * D + lane * 2];
    sx += v0.x; sy += v0.y; mx = fmaxf(mx, v0.x); my = fmaxf(my, v0.y);
  }
  size_t o = (size_t)node * D + lane * 2;
  float2 s2; s2.x = sx; s2.y = sy;
  float2 m2; m2.x = mx; m2.y = my;
  *(float2*)&Sum[o] = s2;
  *(float2*)&Mx[o] = m2;
}

// ---------------------------------------------------------------------------
// Weight conversion: WgT[n][k] = bf16(Wg[k][n]) (384x384), WaT[n][k] (128x384)
// ---------------------------------------------------------------------------
__global__ void convert_wg(const float* __restrict__ Wg, unsigned short* __restrict__ WgT) {
  int idx = blockIdx.x * 256 + threadIdx.x;
  if (idx < 384 * 384) {
    int n = idx / 384, k = idx - n * 384;
    WgT[idx] = f2b(Wg[k * 384 + n]);
  }
}
__global__ void convert_wa(const float* __restrict__ Wa, unsigned short* __restrict__ WaT) {
  int idx = blockIdx.x * 256 + threadIdx.x;
  if (idx < 128 * 384) {
    int n = idx / 384, k = idx - n * 384;
    WaT[idx] = f2b(Wa[k * 128 + n]);
  }
}

// ---------------------------------------------------------------------------
// MFMA epilogue: 64 nodes/block, 4 waves, wave w owns rows 16w..16w+15.
// ---------------------------------------------------------------------------
#define EM 64
__global__ __launch_bounds__(256, 3) void epilogue_mfma(
    const float* __restrict__ Sum, const float* __restrict__ Mx,
    const int* __restrict__ row_ptr, const unsigned short* __restrict__ Wg16,
    const float* __restrict__ bg, const unsigned short* __restrict__ Wa16,
    const float* __restrict__ ba, float* __restrict__ Out) {
  __shared__ unsigned short Ts[EM][392];
  __shared__ float invs[EM];
  __shared__ int cnts[EM];

  const int t = threadIdx.x;
  const int node0 = blockIdx.x * EM;

  if (t < EM) {
    int nd = node0 + t;
    int c = 0;
    if (nd < N_V) c = row_ptr[nd + 1] - row_ptr[nd];
    cnts[t] = c;
    invs[t] = 1.0f / (float)(c > 0 ? c : 1);
  }
  __syncthreads();

  for (int i = t; i < EM * 128; i += 256) {
    int n = i >> 7, j = i & 127;
    int nd = node0 + n;
    float sv = 0.f, mv = 0.f;
    if (nd < N_V) {
      sv = Sum[(size_t)nd * D + j];
      mv = Mx[(size_t)nd * D + j];
    }
    Ts[n][j] = f2b(sv);
    Ts[n][128 + j] = f2b(sv * invs[n]);
    Ts[n][256 + j] = f2b(mv);
  }
  __syncthreads();

  const int wv = t >> 6;
  const int ln = t & 63;
  const int lr = ln & 15;
  const int lq = ln >> 4;
  const int m0 = wv * 16;

  bf16x8 a[12];
#pragma unroll
  for (int ks = 0; ks < 12; ks++)
    a[ks] = *(const bf16x8*)&Ts[m0 + lr][ks * 32 + lq * 8];

  for (int np = 0; np < 12; np++) {
    const int n0 = np * 32;
    f32x4 acc0 = {0.f, 0.f, 0.f, 0.f};
    f32x4 acc1 = {0.f, 0.f, 0.f, 0.f};
    const unsigned short* B0 = &Wg16[(size_t)(n0 + lr) * 384 + lq * 8];
    const unsigned short* B1 = B0 + 16 * 384;
#pragma unroll
    for (int ks = 0; ks < 12; ks++) {
      bf16x8 b0 = *(const bf16x8*)(B0 + ks * 32);
      bf16x8 b1 = *(const bf16x8*)(B1 + ks * 32);
      acc0 = __builtin_amdgcn_mfma_f32_16x16x32_bf16(a[ks], b0, acc0, 0, 0, 0);
      acc1 = __builtin_amdgcn_mfma_f32_16x16x32_bf16(a[ks], b1, acc1, 0, 0, 0);
    }
    float bg0 = bg[n0 + lr];
    float bg1 = bg[n0 + 16 + lr];
#pragma unroll
    for (int r = 0; r < 4; r++) {
      int m = m0 + lq * 4 + r;
      float g0 = 1.f / (1.f + __expf(-(acc0[r] + bg0)));
      float g1 = 1.f / (1.f + __expf(-(acc1[r] + bg1)));
      float t0 = b2f(Ts[m][n0 + lr]);
      float t1 = b2f(Ts[m][n0 + 16 + lr]);
      Ts[m][n0 + lr] = f2b(t0 * g0);
      Ts[m][n0 + 16 + lr] = f2b(t1 * g1);
    }
  }

  bf16x8 a2[12];
#pragma unroll
  for (int ks = 0; ks < 12; ks++)
    a2[ks] = *(const bf16x8*)&Ts[m0 + lr][ks * 32 + lq * 8];

  for (int np = 0; np < 4; np++) {
    const int n0 = np * 32;
    f32x4 acc0 = {0.f, 0.f, 0.f, 0.f};
    f32x4 acc1 = {0.f, 0.f, 0.f, 0.f};
    const unsigned short* B0 = &Wa16[(size_t)(n0 + lr) * 384 + lq * 8];
    const unsigned short* B1 = B0 + 16 * 384;
#pragma unroll
    for (int ks = 0; ks < 12; ks++) {
      bf16x8 b0 = *(const bf16x8*)(B0 + ks * 32);
      bf16x8 b1 = *(const bf16x8*)(B1 + ks * 32);
      acc0 = __builtin_amdgcn_mfma_f32_16x16x32_bf16(a2[ks], b0, acc0, 0, 0, 0);
      acc1 = __builtin_amdgcn_mfma_f32_16x16x32_bf16(a2[ks], b1, acc1, 0, 0, 0);
    }
    float ba0 = ba[n0 + lr];
    float ba1 = ba[n0 + 16 + lr];
#pragma unroll
    for (int r = 0; r < 4; r++) {
      int m = m0 + lq * 4 + r;
      int nd = node0 + m;
      if (nd < N_V) {
        float msk = (cnts[m] > 0) ? 1.f : 0.f;
        size_t o = (size_t)nd * D;
        Out[o + n0 + lr] = (acc0[r] + ba0) * msk;
        Out[o + n0 + 16 + lr] = (acc1[r] + ba1) * msk;
      }
    }
  }
}

// ---------------------------------------------------------------------------
extern "C" void kernel_launch(void* const* d_in, const int* in_sizes, int n_in,
                              void* d_out, int out_size, void* d_ws, size_t ws_size,
                              hipStream_t stream) {
  const float* x_u = (const float*)d_in[0];
  const float* x_v = (const float*)d_in[1];
  const float* W_r1 = (const float*)d_in[2];
  const float* W_r2 = (const float*)d_in[3];
  const float* W_gate = (const float*)d_in[4];
  const float* b_gate = (const float*)d_in[5];
  const float* W_aggr = (const float*)d_in[6];
  const float* b_aggr = (const float*)d_in[7];
  const int* e1 = (const int*)d_in[8];
  const int* e2 = (const int*)d_in[9];
  float* out = (float*)d_out;

  char* ws = (char*)d_ws;
  size_t off = 0;
  float* h = (float*)(ws + off);      off += (size_t)(N_V + N_U) * D * 4;  // 102.4 MB
  float* Sum = (float*)(ws + off);    off += (size_t)N_V * D * 4;          // 51.2 MB
  float* Mx = (float*)(ws + off);     off += (size_t)N_V * D * 4;          // 51.2 MB
  int* colA = (int*)(ws + off);       off += (size_t)ETOT * 4;             // 25.6 MB
  int* row_ptr = (int*)(ws + off);    off += (size_t)(N_V + 1) * 4;
  int* bucketCnt = (int*)(ws + off);  off += NBUCK * 4;
  int* bucketBase = (int*)(ws + off); off += (NBUCK + 1) * 4;
  int* bucketCursor = (int*)(ws + off); off += NBUCK * 4;
  unsigned short* Wg16 = (unsigned short*)(ws + off); off += (size_t)384 * 384 * 2;
  unsigned short* Wa16 = (unsigned short*)(ws + off); off += (size_t)128 * 384 * 2;

  // recs (51.2 MB) aliases Sum+Mx: dead before aggregate_kernel writes them.
  uint2* recs = (uint2*)Sum;

  hipMemsetAsync(bucketCnt, 0, NBUCK * 4, stream);

  linear_kernel<<<N_V / LNT, 256, 0, stream>>>(x_v, W_r2, h, N_V);
  linear_kernel<<<N_U / LNT, 256, 0, stream>>>(x_u, W_r1, h + (size_t)N_V * D, N_U);

  convert_wg<<<(384 * 384 + 255) / 256, 256, 0, stream>>>(W_gate, Wg16);
  convert_wa<<<(128 * 384 + 255) / 256, 256, 0, stream>>>(W_aggr, Wa16);

  bucket_count<<<640, 256, 0, stream>>>(e1, e2, bucketCnt);
  bucket_scan<<<1, 256, 0, stream>>>(bucketCnt, bucketBase, bucketCursor);
  partition_kernel<<<(ETOT + PCHUNK - 1) / PCHUNK, 256, 0, stream>>>(
      e1, e2, bucketCursor, recs);
  bucket_fill<<<NBUCK, 512, 0, stream>>>(recs, bucketBase, row_ptr, colA);

  aggregate_kernel<<<N_V / 4, 256, 0, stream>>>(h, row_ptr, colA, Sum, Mx);

  epilogue_mfma<<<(N_V + EM - 1) / EM, 256, 0, stream>>>(
      Sum, Mx, row_ptr, Wg16, b_gate, Wa16, b_aggr, out);
}

// Round 4
// 961.034 us; speedup vs baseline: 2.7437x; 1.3156x over previous
//
#include <hip/hip_runtime.h>
#include <math.h>

#define N_U 100000
#define N_V 100000
#define D 128
#define E1 3200000
#define E2 3200000
#define ETOT (E1 + E2)

#define NBUCK 196      // buckets of 512 dst nodes: dst >> 9
#define SLACK 35000    // per-bucket record capacity (expected 32768 +/- ~180)
#define PCHUNK 4096    // edges per partition block

typedef __bf16 bf16x8 __attribute__((ext_vector_type(8)));
typedef float f32x4 __attribute__((ext_vector_type(4)));

__device__ __forceinline__ unsigned short f2b(float f) {
  union { float f; unsigned int u; } v; v.f = f;
  unsigned int u = v.u;
  unsigned int r = u + 0x7fffu + ((u >> 16) & 1u);
  return (unsigned short)(r >> 16);
}
__device__ __forceinline__ float b2f(unsigned short s) {
  union { unsigned int u; float f; } v; v.u = ((unsigned int)s) << 16; return v.f;
}

// ---------------------------------------------------------------------------
// Weight transpose+bf16: WT[n][k] = bf16(W[k][n])
// ---------------------------------------------------------------------------
__global__ void convert_w128(const float* __restrict__ W, unsigned short* __restrict__ WT) {
  int idx = blockIdx.x * 256 + threadIdx.x;
  if (idx < 128 * 128) {
    int n = idx >> 7, k = idx & 127;
    WT[idx] = f2b(W[k * 128 + n]);
  }
}
__global__ void convert_wg(const float* __restrict__ Wg, unsigned short* __restrict__ WgT) {
  int idx = blockIdx.x * 256 + threadIdx.x;
  if (idx < 384 * 384) {
    int n = idx / 384, k = idx - n * 384;
    WgT[idx] = f2b(Wg[k * 384 + n]);
  }
}
__global__ void convert_wa(const float* __restrict__ Wa, unsigned short* __restrict__ WaT) {
  int idx = blockIdx.x * 256 + threadIdx.x;
  if (idx < 128 * 384) {
    int n = idx / 384, k = idx - n * 384;
    WaT[idx] = f2b(Wa[k * 128 + n]);
  }
}

// ---------------------------------------------------------------------------
// Linear: Hb(bf16) = X(fp32) @ W  via MFMA. 64 rows/block, 4 waves x 16 rows.
// A: lane holds A[m=lane&15][k=(lane>>4)*8+j] from LDS; B from WT (n-major).
// ---------------------------------------------------------------------------
#define LM 64
__global__ __launch_bounds__(256) void linear_mfma(
    const float* __restrict__ X, const unsigned short* __restrict__ WT,
    unsigned short* __restrict__ Hb, int nrows) {
  __shared__ unsigned short Xs[LM][136];  // 272B rows: 16B-aligned, 2-way-free banks
  const int t = threadIdx.x;
  const int row0 = blockIdx.x * LM;

  for (int i = t * 4; i < LM * 128; i += 1024) {
    int n = i >> 7, j = i & 127;
    int r = row0 + n;
    float4 v = make_float4(0.f, 0.f, 0.f, 0.f);
    if (r < nrows) v = *(const float4*)&X[(size_t)r * 128 + j];
    Xs[n][j] = f2b(v.x);
    Xs[n][j + 1] = f2b(v.y);
    Xs[n][j + 2] = f2b(v.z);
    Xs[n][j + 3] = f2b(v.w);
  }
  __syncthreads();

  const int wv = t >> 6;
  const int ln = t & 63;
  const int lr = ln & 15;
  const int lq = ln >> 4;
  const int m0 = wv * 16;

  bf16x8 a[4];
#pragma unroll
  for (int ks = 0; ks < 4; ks++)
    a[ks] = *(const bf16x8*)&Xs[m0 + lr][ks * 32 + lq * 8];

#pragma unroll
  for (int np = 0; np < 4; np++) {
    const int n0 = np * 32;
    f32x4 acc0 = {0.f, 0.f, 0.f, 0.f};
    f32x4 acc1 = {0.f, 0.f, 0.f, 0.f};
    const unsigned short* B0 = &WT[(size_t)(n0 + lr) * 128 + lq * 8];
    const unsigned short* B1 = B0 + 16 * 128;
#pragma unroll
    for (int ks = 0; ks < 4; ks++) {
      bf16x8 b0 = *(const bf16x8*)(B0 + ks * 32);
      bf16x8 b1 = *(const bf16x8*)(B1 + ks * 32);
      acc0 = __builtin_amdgcn_mfma_f32_16x16x32_bf16(a[ks], b0, acc0, 0, 0, 0);
      acc1 = __builtin_amdgcn_mfma_f32_16x16x32_bf16(a[ks], b1, acc1, 0, 0, 0);
    }
#pragma unroll
    for (int r = 0; r < 4; r++) {
      int grow = row0 + m0 + lq * 4 + r;
      if (grow < nrows) {
        Hb[(size_t)grow * 128 + n0 + lr] = f2b(acc0[r]);
        Hb[(size_t)grow * 128 + n0 + 16 + lr] = f2b(acc1[r]);
      }
    }
  }
}

// ---------------------------------------------------------------------------
// Partition: 4096 edges/block -> LDS hist -> reserve slack ranges -> LDS-stage
// bucket-ordered -> coalesced flush of (enc, dst) into per-bucket slack region.
// ---------------------------------------------------------------------------
__global__ __launch_bounds__(256) void partition_kernel(
    const int* __restrict__ e1, const int* __restrict__ e2,
    int* __restrict__ bucketCursor, uint2* __restrict__ recs) {
  __shared__ int hist[256];
  __shared__ int scan_s[256];
  __shared__ int lstart[256];
  __shared__ int gbase[NBUCK];
  __shared__ int lcur[NBUCK];
  __shared__ uint2 buf[PCHUNK];  // 32 KB

  const int t = threadIdx.x;
  const long base = (long)blockIdx.x * PCHUNK;
  const int n = (int)min((long)PCHUNK, (long)ETOT - base);

  hist[t] = 0;
  __syncthreads();

  uint2 myrec[PCHUNK / 256];
  int myb[PCHUNK / 256];
  int cnt = 0;
#pragma unroll
  for (int k = 0; k < PCHUNK / 256; k++) {
    int idx = t + k * 256;
    if (idx < n) {
      long i = base + idx;
      int enc, dst;
      if (i < E1) {
        dst = e1[E1 + i];
        enc = N_V + e1[i];
      } else {
        long j = i - E1;
        dst = e2[E2 + j];
        enc = e2[j];
      }
      myrec[cnt] = make_uint2((unsigned)enc, (unsigned)dst);
      int b = dst >> 9;
      myb[cnt] = b;
      atomicAdd(&hist[b], 1);
      cnt++;
    }
  }
  __syncthreads();

  int v = hist[t];
  scan_s[t] = v;
  __syncthreads();
  for (int off = 1; off < 256; off <<= 1) {
    int tmp = (t >= off) ? scan_s[t - off] : 0;
    __syncthreads();
    scan_s[t] += tmp;
    __syncthreads();
  }
  lstart[t] = scan_s[t] - v;
  if (t < NBUCK) {
    gbase[t] = atomicAdd(&bucketCursor[t], v);
    lcur[t] = scan_s[t] - v;
  }
  __syncthreads();

  for (int k = 0; k < cnt; k++) {
    int p = atomicAdd(&lcur[myb[k]], 1);
    buf[p] = myrec[k];
  }
  __syncthreads();

  for (int p = t; p < n; p += 256) {
    uint2 r = buf[p];
    int b = (int)(r.y >> 9);
    recs[(size_t)b * SLACK + gbase[b] + (p - lstart[b])] = r;
  }
}

// Scan bucket counts -> compact bases.
__global__ __launch_bounds__(256) void bucket_scan(
    const int* __restrict__ bucketCnt, int* __restrict__ bucketBase) {
  __shared__ int s[256];
  const int t = threadIdx.x;
  int v = (t < NBUCK) ? bucketCnt[t] : 0;
  s[t] = v;
  __syncthreads();
  for (int off = 1; off < 256; off <<= 1) {
    int tmp = (t >= off) ? s[t - off] : 0;
    __syncthreads();
    s[t] += tmp;
    __syncthreads();
  }
  if (t < NBUCK) bucketBase[t] = s[t] - v;
  if (t == 255) bucketBase[NBUCK] = s[255];
}

// One block per bucket: per-node hist+scan -> row_ptr; L2-local scatter of col.
__global__ __launch_bounds__(512) void bucket_fill(
    const uint2* __restrict__ recs, const int* __restrict__ bucketCnt,
    const int* __restrict__ bucketBase, int* __restrict__ row_ptr,
    int* __restrict__ col) {
  __shared__ int hist[512];
  __shared__ int s[512];
  __shared__ int cur[512];
  const int t = threadIdx.x;
  const int b = blockIdx.x;
  const size_t slack = (size_t)b * SLACK;
  const int n = bucketCnt[b];
  const int outBase = bucketBase[b];
  const int n0 = b << 9;

  hist[t] = 0;
  __syncthreads();
  for (int p = t; p < n; p += 512)
    atomicAdd(&hist[recs[slack + p].y - n0], 1);
  __syncthreads();

  int v = hist[t];
  s[t] = v;
  __syncthreads();
  for (int off = 1; off < 512; off <<= 1) {
    int tmp = (t >= off) ? s[t - off] : 0;
    __syncthreads();
    s[t] += tmp;
    __syncthreads();
  }
  int excl = s[t] - v;
  cur[t] = excl;
  int nd = n0 + t;
  if (nd < N_V) row_ptr[nd] = outBase + excl;
  if (b == 0 && t == 0) row_ptr[N_V] = ETOT;
  __syncthreads();

  for (int p = t; p < n; p += 512) {
    uint2 r = recs[slack + p];
    int q = atomicAdd(&cur[r.y - n0], 1);
    col[outBase + q] = r.x;
  }
}

// ---------------------------------------------------------------------------
// Aggregation over bf16 H: one wave per dst node; lane l holds feats 2l,2l+1
// (one packed uint per row). fp32 accumulate, bf16 packed store.
// ---------------------------------------------------------------------------
__global__ __launch_bounds__(256) void aggregate_kernel(
    const unsigned short* __restrict__ Hb, const int* __restrict__ row_ptr,
    const int* __restrict__ col, unsigned int* __restrict__ SumB,
    unsigned int* __restrict__ MxB) {
  const int node = blockIdx.x * 4 + (threadIdx.x >> 6);
  const int lane = threadIdx.x & 63;
  const int start = row_ptr[node];
  const int end = row_ptr[node + 1];

  float sx = 0.f, sy = 0.f;
  float mx = 0.f, my = 0.f;

  int i = start;
  for (; i + 3 < end; i += 4) {
    int c0 = col[i], c1 = col[i + 1], c2 = col[i + 2], c3 = col[i + 3];
    unsigned v0 = *(const unsigned*)&Hb[(size_t)c0 * D + lane * 2];
    unsigned v1 = *(const unsigned*)&Hb[(size_t)c1 * D + lane * 2];
    unsigned v2 = *(const unsigned*)&Hb[(size_t)c2 * D + lane * 2];
    unsigned v3 = *(const unsigned*)&Hb[(size_t)c3 * D + lane * 2];
    float x0 = b2f((unsigned short)v0), y0 = b2f((unsigned short)(v0 >> 16));
    float x1 = b2f((unsigned short)v1), y1 = b2f((unsigned short)(v1 >> 16));
    float x2 = b2f((unsigned short)v2), y2 = b2f((unsigned short)(v2 >> 16));
    float x3 = b2f((unsigned short)v3), y3 = b2f((unsigned short)(v3 >> 16));
    sx += x0; sy += y0; mx = fmaxf(mx, x0); my = fmaxf(my, y0);
    sx += x1; sy += y1; mx = fmaxf(mx, x1); my = fmaxf(my, y1);
    sx += x2; sy += y2; mx = fmaxf(mx, x2); my = fmaxf(my, y2);
    sx += x3; sy += y3; mx = fmaxf(mx, x3); my = fmaxf(my, y3);
  }
  for (; i < end; i++) {
    int c0 = col[i];
    unsigned v0 = *(const unsigned*)&Hb[(size_t)c0 * D + lane * 2];
    float x0 = b2f((unsigned short)v0), y0 = b2f((unsigned short)(v0 >> 16));
    sx += x0; sy += y0; mx = fmaxf(mx, x0); my = fmaxf(my, y0);
  }
  size_t o = (size_t)node * 64 + lane;
  SumB[o] = (unsigned)f2b(sx) | ((unsigned)f2b(sy) << 16);
  MxB[o] = (unsigned)f2b(mx) | ((unsigned)f2b(my) << 16);
}

// ---------------------------------------------------------------------------
// MFMA epilogue: 64 nodes/block, 4 waves, wave w owns rows 16w..16w+15.
// ---------------------------------------------------------------------------
#define EM 64
__global__ __launch_bounds__(256, 3) void epilogue_mfma(
    const unsigned short* __restrict__ SumB, const unsigned short* __restrict__ MxB,
    const int* __restrict__ row_ptr, const unsigned short* __restrict__ Wg16,
    const float* __restrict__ bg, const unsigned short* __restrict__ Wa16,
    const float* __restrict__ ba, float* __restrict__ Out) {
  __shared__ unsigned short Ts[EM][392];
  __shared__ float invs[EM];
  __shared__ int cnts[EM];

  const int t = threadIdx.x;
  const int node0 = blockIdx.x * EM;

  if (t < EM) {
    int nd = node0 + t;
    int c = 0;
    if (nd < N_V) c = row_ptr[nd + 1] - row_ptr[nd];
    cnts[t] = c;
    invs[t] = 1.0f / (float)(c > 0 ? c : 1);
  }
  __syncthreads();

  for (int i = t; i < EM * 128; i += 256) {
    int n = i >> 7, j = i & 127;
    int nd = node0 + n;
    unsigned short sv = 0, mv = 0;
    if (nd < N_V) {
      sv = SumB[(size_t)nd * D + j];
      mv = MxB[(size_t)nd * D + j];
    }
    Ts[n][j] = sv;
    Ts[n][128 + j] = f2b(b2f(sv) * invs[n]);
    Ts[n][256 + j] = mv;
  }
  __syncthreads();

  const int wv = t >> 6;
  const int ln = t & 63;
  const int lr = ln & 15;
  const int lq = ln >> 4;
  const int m0 = wv * 16;

  bf16x8 a[12];
#pragma unroll
  for (int ks = 0; ks < 12; ks++)
    a[ks] = *(const bf16x8*)&Ts[m0 + lr][ks * 32 + lq * 8];

  for (int np = 0; np < 12; np++) {
    const int n0 = np * 32;
    f32x4 acc0 = {0.f, 0.f, 0.f, 0.f};
    f32x4 acc1 = {0.f, 0.f, 0.f, 0.f};
    const unsigned short* B0 = &Wg16[(size_t)(n0 + lr) * 384 + lq * 8];
    const unsigned short* B1 = B0 + 16 * 384;
#pragma unroll
    for (int ks = 0; ks < 12; ks++) {
      bf16x8 b0 = *(const bf16x8*)(B0 + ks * 32);
      bf16x8 b1 = *(const bf16x8*)(B1 + ks * 32);
      acc0 = __builtin_amdgcn_mfma_f32_16x16x32_bf16(a[ks], b0, acc0, 0, 0, 0);
      acc1 = __builtin_amdgcn_mfma_f32_16x16x32_bf16(a[ks], b1, acc1, 0, 0, 0);
    }
    float bg0 = bg[n0 + lr];
    float bg1 = bg[n0 + 16 + lr];
#pragma unroll
    for (int r = 0; r < 4; r++) {
      int m = m0 + lq * 4 + r;
      float g0 = 1.f / (1.f + __expf(-(acc0[r] + bg0)));
      float g1 = 1.f / (1.f + __expf(-(acc1[r] + bg1)));
      float t0 = b2f(Ts[m][n0 + lr]);
      float t1 = b2f(Ts[m][n0 + 16 + lr]);
      Ts[m][n0 + lr] = f2b(t0 * g0);
      Ts[m][n0 + 16 + lr] = f2b(t1 * g1);
    }
  }

  bf16x8 a2[12];
#pragma unroll
  for (int ks = 0; ks < 12; ks++)
    a2[ks] = *(const bf16x8*)&Ts[m0 + lr][ks * 32 + lq * 8];

  for (int np = 0; np < 4; np++) {
    const int n0 = np * 32;
    f32x4 acc0 = {0.f, 0.f, 0.f, 0.f};
    f32x4 acc1 = {0.f, 0.f, 0.f, 0.f};
    const unsigned short* B0 = &Wa16[(size_t)(n0 + lr) * 384 + lq * 8];
    const unsigned short* B1 = B0 + 16 * 384;
#pragma unroll
    for (int ks = 0; ks < 12; ks++) {
      bf16x8 b0 = *(const bf16x8*)(B0 + ks * 32);
      bf16x8 b1 = *(const bf16x8*)(B1 + ks * 32);
      acc0 = __builtin_amdgcn_mfma_f32_16x16x32_bf16(a2[ks], b0, acc0, 0, 0, 0);
      acc1 = __builtin_amdgcn_mfma_f32_16x16x32_bf16(a2[ks], b1, acc1, 0, 0, 0);
    }
    float ba0 = ba[n0 + lr];
    float ba1 = ba[n0 + 16 + lr];
#pragma unroll
    for (int r = 0; r < 4; r++) {
      int m = m0 + lq * 4 + r;
      int nd = node0 + m;
      if (nd < N_V) {
        float msk = (cnts[m] > 0) ? 1.f : 0.f;
        size_t o = (size_t)nd * D;
        Out[o + n0 + lr] = (acc0[r] + ba0) * msk;
        Out[o + n0 + 16 + lr] = (acc1[r] + ba1) * msk;
      }
    }
  }
}

// ---------------------------------------------------------------------------
extern "C" void kernel_launch(void* const* d_in, const int* in_sizes, int n_in,
                              void* d_out, int out_size, void* d_ws, size_t ws_size,
                              hipStream_t stream) {
  const float* x_u = (const float*)d_in[0];
  const float* x_v = (const float*)d_in[1];
  const float* W_r1 = (const float*)d_in[2];
  const float* W_r2 = (const float*)d_in[3];
  const float* W_gate = (const float*)d_in[4];
  const float* b_gate = (const float*)d_in[5];
  const float* W_aggr = (const float*)d_in[6];
  const float* b_aggr = (const float*)d_in[7];
  const int* e1 = (const int*)d_in[8];
  const int* e2 = (const int*)d_in[9];
  float* out = (float*)d_out;

  char* ws = (char*)d_ws;
  size_t off = 0;
  unsigned short* Hb = (unsigned short*)(ws + off); off += (size_t)(N_V + N_U) * D * 2;  // 51.2 MB
  unsigned int* SumB = (unsigned int*)(ws + off);   off += (size_t)N_V * D * 2;         // 25.6 MB
  unsigned int* MxB = (unsigned int*)(ws + off);    off += (size_t)N_V * D * 2;         // 25.6 MB
  int* colA = (int*)(ws + off);        off += (size_t)ETOT * 4;                         // 25.6 MB
  uint2* recs = (uint2*)(ws + off);    off += (size_t)NBUCK * SLACK * 8;                // 54.9 MB
  int* row_ptr = (int*)(ws + off);     off += (size_t)(N_V + 1) * 4;
  int* bucketCursor = (int*)(ws + off); off += NBUCK * 4;
  int* bucketBase = (int*)(ws + off);  off += (NBUCK + 1) * 4;
  unsigned short* Wg16 = (unsigned short*)(ws + off); off += (size_t)384 * 384 * 2;
  unsigned short* Wa16 = (unsigned short*)(ws + off); off += (size_t)128 * 384 * 2;
  unsigned short* Wr1T = (unsigned short*)(ws + off); off += (size_t)128 * 128 * 2;
  unsigned short* Wr2T = (unsigned short*)(ws + off); off += (size_t)128 * 128 * 2;

  hipMemsetAsync(bucketCursor, 0, NBUCK * 4, stream);

  convert_w128<<<64, 256, 0, stream>>>(W_r1, Wr1T);
  convert_w128<<<64, 256, 0, stream>>>(W_r2, Wr2T);
  convert_wg<<<(384 * 384 + 255) / 256, 256, 0, stream>>>(W_gate, Wg16);
  convert_wa<<<(128 * 384 + 255) / 256, 256, 0, stream>>>(W_aggr, Wa16);

  // Hb rows [0,N_V) = x_v @ W_r2 ; rows [N_V, N_V+N_U) = x_u @ W_r1
  linear_mfma<<<(N_V + LM - 1) / LM, 256, 0, stream>>>(x_v, Wr2T, Hb, N_V);
  linear_mfma<<<(N_U + LM - 1) / LM, 256, 0, stream>>>(x_u, Wr1T, Hb + (size_t)N_V * D, N_U);

  partition_kernel<<<(ETOT + PCHUNK - 1) / PCHUNK, 256, 0, stream>>>(
      e1, e2, bucketCursor, recs);
  bucket_scan<<<1, 256, 0, stream>>>(bucketCursor, bucketBase);
  bucket_fill<<<NBUCK, 512, 0, stream>>>(recs, bucketCursor, bucketBase, row_ptr, colA);

  aggregate_kernel<<<N_V / 4, 256, 0, stream>>>(Hb, row_ptr, colA, SumB, MxB);

  epilogue_mfma<<<(N_V + EM - 1) / EM, 256, 0, stream>>>(
      (const unsigned short*)SumB, (const unsigned short*)MxB, row_ptr,
      Wg16, b_gate, Wa16, b_aggr, out);
}

// Round 5
// 830.782 us; speedup vs baseline: 3.1738x; 1.1568x over previous
//
#include <hip/hip_runtime.h>
#include <math.h>

#define N_U 100000
#define N_V 100000
#define D 128
#define E1 3200000
#define E2 3200000
#define ETOT (E1 + E2)

#define NBUCK 196      // buckets of 512 dst nodes: dst >> 9
#define SLACK 35000    // per-bucket record capacity (expected 32768 +/- ~180)
#define PCHUNK 4096    // edges per partition block

typedef __bf16 bf16x8 __attribute__((ext_vector_type(8)));
typedef float f32x4 __attribute__((ext_vector_type(4)));

__device__ __forceinline__ unsigned short f2b(float f) {
  union { float f; unsigned int u; } v; v.f = f;
  unsigned int u = v.u;
  unsigned int r = u + 0x7fffu + ((u >> 16) & 1u);
  return (unsigned short)(r >> 16);
}
__device__ __forceinline__ float b2f(unsigned short s) {
  union { unsigned int u; float f; } v; v.u = ((unsigned int)s) << 16; return v.f;
}

// ---------------------------------------------------------------------------
// Weight transpose+bf16: WT[n][k] = bf16(W[k][n])
// ---------------------------------------------------------------------------
__global__ void convert_w128(const float* __restrict__ W, unsigned short* __restrict__ WT) {
  int idx = blockIdx.x * 256 + threadIdx.x;
  if (idx < 128 * 128) {
    int n = idx >> 7, k = idx & 127;
    WT[idx] = f2b(W[k * 128 + n]);
  }
}
__global__ void convert_wg(const float* __restrict__ Wg, unsigned short* __restrict__ WgT) {
  int idx = blockIdx.x * 256 + threadIdx.x;
  if (idx < 384 * 384) {
    int n = idx / 384, k = idx - n * 384;
    WgT[idx] = f2b(Wg[k * 384 + n]);
  }
}
__global__ void convert_wa(const float* __restrict__ Wa, unsigned short* __restrict__ WaT) {
  int idx = blockIdx.x * 256 + threadIdx.x;
  if (idx < 128 * 384) {
    int n = idx / 384, k = idx - n * 384;
    WaT[idx] = f2b(Wa[k * 128 + n]);
  }
}

// ---------------------------------------------------------------------------
// Linear: Hb(bf16) = X(fp32) @ W  via MFMA. 64 rows/block, 4 waves x 16 rows.
// ---------------------------------------------------------------------------
#define LM 64
__global__ __launch_bounds__(256) void linear_mfma(
    const float* __restrict__ X, const unsigned short* __restrict__ WT,
    unsigned short* __restrict__ Hb, int nrows) {
  __shared__ unsigned short Xs[LM][136];
  const int t = threadIdx.x;
  const int row0 = blockIdx.x * LM;

  for (int i = t * 4; i < LM * 128; i += 1024) {
    int n = i >> 7, j = i & 127;
    int r = row0 + n;
    float4 v = make_float4(0.f, 0.f, 0.f, 0.f);
    if (r < nrows) v = *(const float4*)&X[(size_t)r * 128 + j];
    Xs[n][j] = f2b(v.x);
    Xs[n][j + 1] = f2b(v.y);
    Xs[n][j + 2] = f2b(v.z);
    Xs[n][j + 3] = f2b(v.w);
  }
  __syncthreads();

  const int wv = t >> 6;
  const int ln = t & 63;
  const int lr = ln & 15;
  const int lq = ln >> 4;
  const int m0 = wv * 16;

  bf16x8 a[4];
#pragma unroll
  for (int ks = 0; ks < 4; ks++)
    a[ks] = *(const bf16x8*)&Xs[m0 + lr][ks * 32 + lq * 8];

#pragma unroll
  for (int np = 0; np < 4; np++) {
    const int n0 = np * 32;
    f32x4 acc0 = {0.f, 0.f, 0.f, 0.f};
    f32x4 acc1 = {0.f, 0.f, 0.f, 0.f};
    const unsigned short* B0 = &WT[(size_t)(n0 + lr) * 128 + lq * 8];
    const unsigned short* B1 = B0 + 16 * 128;
#pragma unroll
    for (int ks = 0; ks < 4; ks++) {
      bf16x8 b0 = *(const bf16x8*)(B0 + ks * 32);
      bf16x8 b1 = *(const bf16x8*)(B1 + ks * 32);
      acc0 = __builtin_amdgcn_mfma_f32_16x16x32_bf16(a[ks], b0, acc0, 0, 0, 0);
      acc1 = __builtin_amdgcn_mfma_f32_16x16x32_bf16(a[ks], b1, acc1, 0, 0, 0);
    }
#pragma unroll
    for (int r = 0; r < 4; r++) {
      int grow = row0 + m0 + lq * 4 + r;
      if (grow < nrows) {
        Hb[(size_t)grow * 128 + n0 + lr] = f2b(acc0[r]);
        Hb[(size_t)grow * 128 + n0 + 16 + lr] = f2b(acc1[r]);
      }
    }
  }
}

// ---------------------------------------------------------------------------
// Partition: 4096 edges/block -> LDS hist -> reserve slack ranges -> LDS-stage
// bucket-ordered -> coalesced flush of (enc, dst) into per-bucket slack region.
// ---------------------------------------------------------------------------
__global__ __launch_bounds__(256) void partition_kernel(
    const int* __restrict__ e1, const int* __restrict__ e2,
    int* __restrict__ bucketCursor, uint2* __restrict__ recs) {
  __shared__ int hist[256];
  __shared__ int scan_s[256];
  __shared__ int lstart[256];
  __shared__ int gbase[NBUCK];
  __shared__ int lcur[NBUCK];
  __shared__ uint2 buf[PCHUNK];  // 32 KB

  const int t = threadIdx.x;
  const long base = (long)blockIdx.x * PCHUNK;
  const int n = (int)min((long)PCHUNK, (long)ETOT - base);

  hist[t] = 0;
  __syncthreads();

  uint2 myrec[PCHUNK / 256];
  int myb[PCHUNK / 256];
  int cnt = 0;
#pragma unroll
  for (int k = 0; k < PCHUNK / 256; k++) {
    int idx = t + k * 256;
    if (idx < n) {
      long i = base + idx;
      int enc, dst;
      if (i < E1) {
        dst = e1[E1 + i];
        enc = N_V + e1[i];
      } else {
        long j = i - E1;
        dst = e2[E2 + j];
        enc = e2[j];
      }
      myrec[cnt] = make_uint2((unsigned)enc, (unsigned)dst);
      int b = dst >> 9;
      myb[cnt] = b;
      atomicAdd(&hist[b], 1);
      cnt++;
    }
  }
  __syncthreads();

  int v = hist[t];
  scan_s[t] = v;
  __syncthreads();
  for (int off = 1; off < 256; off <<= 1) {
    int tmp = (t >= off) ? scan_s[t - off] : 0;
    __syncthreads();
    scan_s[t] += tmp;
    __syncthreads();
  }
  lstart[t] = scan_s[t] - v;
  if (t < NBUCK) {
    gbase[t] = atomicAdd(&bucketCursor[t], v);
    lcur[t] = scan_s[t] - v;
  }
  __syncthreads();

  for (int k = 0; k < cnt; k++) {
    int p = atomicAdd(&lcur[myb[k]], 1);
    buf[p] = myrec[k];
  }
  __syncthreads();

  for (int p = t; p < n; p += 256) {
    uint2 r = buf[p];
    int b = (int)(r.y >> 9);
    recs[(size_t)b * SLACK + gbase[b] + (p - lstart[b])] = r;
  }
}

// Scan bucket counts -> compact bases.
__global__ __launch_bounds__(256) void bucket_scan(
    const int* __restrict__ bucketCnt, int* __restrict__ bucketBase) {
  __shared__ int s[256];
  const int t = threadIdx.x;
  int v = (t < NBUCK) ? bucketCnt[t] : 0;
  s[t] = v;
  __syncthreads();
  for (int off = 1; off < 256; off <<= 1) {
    int tmp = (t >= off) ? s[t - off] : 0;
    __syncthreads();
    s[t] += tmp;
    __syncthreads();
  }
  if (t < NBUCK) bucketBase[t] = s[t] - v;
  if (t == 255) bucketBase[NBUCK] = s[255];
}

// One block per bucket: per-node hist+scan -> row_ptr; L2-local scatter of col.
__global__ __launch_bounds__(512) void bucket_fill(
    const uint2* __restrict__ recs, const int* __restrict__ bucketCnt,
    const int* __restrict__ bucketBase, int* __restrict__ row_ptr,
    int* __restrict__ col) {
  __shared__ int hist[512];
  __shared__ int s[512];
  __shared__ int cur[512];
  const int t = threadIdx.x;
  const int b = blockIdx.x;
  const size_t slack = (size_t)b * SLACK;
  const int n = bucketCnt[b];
  const int outBase = bucketBase[b];
  const int n0 = b << 9;

  hist[t] = 0;
  __syncthreads();
  for (int p = t; p < n; p += 512)
    atomicAdd(&hist[recs[slack + p].y - n0], 1);
  __syncthreads();

  int v = hist[t];
  s[t] = v;
  __syncthreads();
  for (int off = 1; off < 512; off <<= 1) {
    int tmp = (t >= off) ? s[t - off] : 0;
    __syncthreads();
    s[t] += tmp;
    __syncthreads();
  }
  int excl = s[t] - v;
  cur[t] = excl;
  int nd = n0 + t;
  if (nd < N_V) row_ptr[nd] = outBase + excl;
  if (b == 0 && t == 0) row_ptr[N_V] = ETOT;
  __syncthreads();

  for (int p = t; p < n; p += 512) {
    uint2 r = recs[slack + p];
    int q = atomicAdd(&cur[r.y - n0], 1);
    col[outBase + q] = r.x;
  }
}

// ---------------------------------------------------------------------------
// Aggregation over bf16 H: one wave per dst node; lane l holds feats 2l,2l+1.
// ---------------------------------------------------------------------------
__global__ __launch_bounds__(256) void aggregate_kernel(
    const unsigned short* __restrict__ Hb, const int* __restrict__ row_ptr,
    const int* __restrict__ col, unsigned int* __restrict__ SumB,
    unsigned int* __restrict__ MxB) {
  const int node = blockIdx.x * 4 + (threadIdx.x >> 6);
  const int lane = threadIdx.x & 63;
  const int start = row_ptr[node];
  const int end = row_ptr[node + 1];

  float sx = 0.f, sy = 0.f;
  float mx = 0.f, my = 0.f;

  int i = start;
  for (; i + 3 < end; i += 4) {
    int c0 = col[i], c1 = col[i + 1], c2 = col[i + 2], c3 = col[i + 3];
    unsigned v0 = *(const unsigned*)&Hb[(size_t)c0 * D + lane * 2];
    unsigned v1 = *(const unsigned*)&Hb[(size_t)c1 * D + lane * 2];
    unsigned v2 = *(const unsigned*)&Hb[(size_t)c2 * D + lane * 2];
    unsigned v3 = *(const unsigned*)&Hb[(size_t)c3 * D + lane * 2];
    float x0 = b2f((unsigned short)v0), y0 = b2f((unsigned short)(v0 >> 16));
    float x1 = b2f((unsigned short)v1), y1 = b2f((unsigned short)(v1 >> 16));
    float x2 = b2f((unsigned short)v2), y2 = b2f((unsigned short)(v2 >> 16));
    float x3 = b2f((unsigned short)v3), y3 = b2f((unsigned short)(v3 >> 16));
    sx += x0; sy += y0; mx = fmaxf(mx, x0); my = fmaxf(my, y0);
    sx += x1; sy += y1; mx = fmaxf(mx, x1); my = fmaxf(my, y1);
    sx += x2; sy += y2; mx = fmaxf(mx, x2); my = fmaxf(my, y2);
    sx += x3; sy += y3; mx = fmaxf(mx, x3); my = fmaxf(my, y3);
  }
  for (; i < end; i++) {
    int c0 = col[i];
    unsigned v0 = *(const unsigned*)&Hb[(size_t)c0 * D + lane * 2];
    float x0 = b2f((unsigned short)v0), y0 = b2f((unsigned short)(v0 >> 16));
    sx += x0; sy += y0; mx = fmaxf(mx, x0); my = fmaxf(my, y0);
  }
  size_t o = (size_t)node * 64 + lane;
  SumB[o] = (unsigned)f2b(sx) | ((unsigned)f2b(sy) << 16);
  MxB[o] = (unsigned)f2b(mx) | ((unsigned)f2b(my) << 16);
}

// ---------------------------------------------------------------------------
// MFMA epilogue v2: 64 nodes/block, 4 waves ALL on the same 64 rows (wave w
// owns rows 16w..16w+15 as before), but B streamed through LDS k-panels so
// the block reads Wg/Wa once (coalesced) instead of once per wave (scattered).
// Per k-chunk (32): stage B panel [n][32] -> each wave: 1 A-frag + n-tile
// ds_read_b128 B-frags + independent-accumulator MFMAs (acc for ALL n in regs).
// ---------------------------------------------------------------------------
#define EM 64
__global__ __launch_bounds__(256, 2) void epilogue_mfma(
    const unsigned short* __restrict__ SumB, const unsigned short* __restrict__ MxB,
    const int* __restrict__ row_ptr, const unsigned short* __restrict__ Wg16,
    const float* __restrict__ bg, const unsigned short* __restrict__ Wa16,
    const float* __restrict__ ba, float* __restrict__ Out) {
  __shared__ unsigned short Ts[EM][392];   // 50176 B
  __shared__ unsigned short Bp[384 * 32];  // 24576 B panel
  __shared__ float invs[EM];
  __shared__ int cnts[EM];                 // total ~75.3 KB -> 2 blocks/CU

  const int t = threadIdx.x;
  const int node0 = blockIdx.x * EM;

  if (t < EM) {
    int nd = node0 + t;
    int c = 0;
    if (nd < N_V) c = row_ptr[nd + 1] - row_ptr[nd];
    cnts[t] = c;
    invs[t] = 1.0f / (float)(c > 0 ? c : 1);
  }
  __syncthreads();

  for (int i = t; i < EM * 128; i += 256) {
    int n = i >> 7, j = i & 127;
    int nd = node0 + n;
    unsigned short sv = 0, mv = 0;
    if (nd < N_V) {
      sv = SumB[(size_t)nd * D + j];
      mv = MxB[(size_t)nd * D + j];
    }
    Ts[n][j] = sv;
    Ts[n][128 + j] = f2b(b2f(sv) * invs[n]);
    Ts[n][256 + j] = mv;
  }

  const int wv = t >> 6;
  const int ln = t & 63;
  const int lr = ln & 15;   // A-row / B-col / C-col
  const int lq = ln >> 4;   // quad
  const int m0 = wv * 16;

  // ---- GEMM1: acc[nt] over all 24 n-tiles (384 cols), K-chunked by 32 ----
  f32x4 acc[24];
#pragma unroll
  for (int nt = 0; nt < 24; nt++) acc[nt] = (f32x4){0.f, 0.f, 0.f, 0.f};

  for (int kc = 0; kc < 12; kc++) {
    __syncthreads();  // Ts staging done (kc=0) / previous panel consumed
    // stage B panel: Bp[n*32 + kk] = Wg16[n*384 + kc*32 + kk], n=0..383
    {
      const unsigned short* src = Wg16 + kc * 32;
      for (int i = t; i < 1536; i += 256) {       // 1536 x 16B slots
        int n = i >> 2, part = (i & 3) * 8;
        *(uint4*)&Bp[n * 32 + part] = *(const uint4*)(src + (size_t)n * 384 + part);
      }
    }
    __syncthreads();
    bf16x8 af = *(const bf16x8*)&Ts[m0 + lr][kc * 32 + lq * 8];
#pragma unroll
    for (int nt = 0; nt < 24; nt++) {
      bf16x8 bf = *(const bf16x8*)&Bp[(nt * 16 + lr) * 32 + lq * 8];
      acc[nt] = __builtin_amdgcn_mfma_f32_16x16x32_bf16(af, bf, acc[nt], 0, 0, 0);
    }
  }

  // gate + TG in-place (wave-private rows -> no barrier needed here)
#pragma unroll
  for (int nt = 0; nt < 24; nt++) {
    int cg = nt * 16 + lr;
    float bgv = bg[cg];
#pragma unroll
    for (int r = 0; r < 4; r++) {
      int m = m0 + lq * 4 + r;
      float g = 1.f / (1.f + __expf(-(acc[nt][r] + bgv)));
      Ts[m][cg] = f2b(b2f(Ts[m][cg]) * g);
    }
  }

  // ---- GEMM2: out = TG @ Wa + ba (8 n-tiles), same panel scheme ----
  f32x4 acc2[8];
#pragma unroll
  for (int nt = 0; nt < 8; nt++) acc2[nt] = (f32x4){0.f, 0.f, 0.f, 0.f};

  for (int kc = 0; kc < 12; kc++) {
    __syncthreads();  // previous panel consumed / all waves' gating done
    {
      const unsigned short* src = Wa16 + kc * 32;
      for (int i = t; i < 512; i += 256) {        // 512 x 16B slots
        int n = i >> 2, part = (i & 3) * 8;
        *(uint4*)&Bp[n * 32 + part] = *(const uint4*)(src + (size_t)n * 384 + part);
      }
    }
    __syncthreads();
    bf16x8 af = *(const bf16x8*)&Ts[m0 + lr][kc * 32 + lq * 8];
#pragma unroll
    for (int nt = 0; nt < 8; nt++) {
      bf16x8 bf = *(const bf16x8*)&Bp[(nt * 16 + lr) * 32 + lq * 8];
      acc2[nt] = __builtin_amdgcn_mfma_f32_16x16x32_bf16(af, bf, acc2[nt], 0, 0, 0);
    }
  }

#pragma unroll
  for (int nt = 0; nt < 8; nt++) {
    int cg = nt * 16 + lr;
    float bav = ba[cg];
#pragma unroll
    for (int r = 0; r < 4; r++) {
      int m = m0 + lq * 4 + r;
      int nd = node0 + m;
      if (nd < N_V) {
        float msk = (cnts[m] > 0) ? 1.f : 0.f;
        Out[(size_t)nd * D + cg] = (acc2[nt][r] + bav) * msk;
      }
    }
  }
}

// ---------------------------------------------------------------------------
extern "C" void kernel_launch(void* const* d_in, const int* in_sizes, int n_in,
                              void* d_out, int out_size, void* d_ws, size_t ws_size,
                              hipStream_t stream) {
  const float* x_u = (const float*)d_in[0];
  const float* x_v = (const float*)d_in[1];
  const float* W_r1 = (const float*)d_in[2];
  const float* W_r2 = (const float*)d_in[3];
  const float* W_gate = (const float*)d_in[4];
  const float* b_gate = (const float*)d_in[5];
  const float* W_aggr = (const float*)d_in[6];
  const float* b_aggr = (const float*)d_in[7];
  const int* e1 = (const int*)d_in[8];
  const int* e2 = (const int*)d_in[9];
  float* out = (float*)d_out;

  char* ws = (char*)d_ws;
  size_t off = 0;
  unsigned short* Hb = (unsigned short*)(ws + off); off += (size_t)(N_V + N_U) * D * 2;
  unsigned int* SumB = (unsigned int*)(ws + off);   off += (size_t)N_V * D * 2;
  unsigned int* MxB = (unsigned int*)(ws + off);    off += (size_t)N_V * D * 2;
  int* colA = (int*)(ws + off);        off += (size_t)ETOT * 4;
  uint2* recs = (uint2*)(ws + off);    off += (size_t)NBUCK * SLACK * 8;
  int* row_ptr = (int*)(ws + off);     off += (size_t)(N_V + 1) * 4;
  int* bucketCursor = (int*)(ws + off); off += NBUCK * 4;
  int* bucketBase = (int*)(ws + off);  off += (NBUCK + 1) * 4;
  unsigned short* Wg16 = (unsigned short*)(ws + off); off += (size_t)384 * 384 * 2;
  unsigned short* Wa16 = (unsigned short*)(ws + off); off += (size_t)128 * 384 * 2;
  unsigned short* Wr1T = (unsigned short*)(ws + off); off += (size_t)128 * 128 * 2;
  unsigned short* Wr2T = (unsigned short*)(ws + off); off += (size_t)128 * 128 * 2;

  hipMemsetAsync(bucketCursor, 0, NBUCK * 4, stream);

  convert_w128<<<64, 256, 0, stream>>>(W_r1, Wr1T);
  convert_w128<<<64, 256, 0, stream>>>(W_r2, Wr2T);
  convert_wg<<<(384 * 384 + 255) / 256, 256, 0, stream>>>(W_gate, Wg16);
  convert_wa<<<(128 * 384 + 255) / 256, 256, 0, stream>>>(W_aggr, Wa16);

  linear_mfma<<<(N_V + LM - 1) / LM, 256, 0, stream>>>(x_v, Wr2T, Hb, N_V);
  linear_mfma<<<(N_U + LM - 1) / LM, 256, 0, stream>>>(x_u, Wr1T, Hb + (size_t)N_V * D, N_U);

  partition_kernel<<<(ETOT + PCHUNK - 1) / PCHUNK, 256, 0, stream>>>(
      e1, e2, bucketCursor, recs);
  bucket_scan<<<1, 256, 0, stream>>>(bucketCursor, bucketBase);
  bucket_fill<<<NBUCK, 512, 0, stream>>>(recs, bucketCursor, bucketBase, row_ptr, colA);

  aggregate_kernel<<<N_V / 4, 256, 0, stream>>>(Hb, row_ptr, colA, SumB, MxB);

  epilogue_mfma<<<(N_V + EM - 1) / EM, 256, 0, stream>>>(
      (const unsigned short*)SumB, (const unsigned short*)MxB, row_ptr,
      Wg16, b_gate, Wa16, b_aggr, out);
}

// Round 6
// 824.254 us; speedup vs baseline: 3.1990x; 1.0079x over previous
//
#include <hip/hip_runtime.h>
#include <math.h>

#define N_U 100000
#define N_V 100000
#define D 128
#define E1 3200000
#define E2 3200000
#define ETOT (E1 + E2)

#define NBUCK 196      // buckets of 512 dst nodes: dst >> 9
#define SLACK 35000    // per-bucket record capacity (expected 32768 +/- ~180)
#define PCHUNK 4096    // edges per partition block

typedef __bf16 bf16x8 __attribute__((ext_vector_type(8)));
typedef float f32x4 __attribute__((ext_vector_type(4)));

__device__ __forceinline__ unsigned short f2b(float f) {
  union { float f; unsigned int u; } v; v.f = f;
  unsigned int u = v.u;
  unsigned int r = u + 0x7fffu + ((u >> 16) & 1u);
  return (unsigned short)(r >> 16);
}
__device__ __forceinline__ float b2f(unsigned short s) {
  union { unsigned int u; float f; } v; v.u = ((unsigned int)s) << 16; return v.f;
}

// ---------------------------------------------------------------------------
// Weight transpose+bf16: WT[n][k] = bf16(W[k][n])
// ---------------------------------------------------------------------------
__global__ void convert_w128(const float* __restrict__ W, unsigned short* __restrict__ WT) {
  int idx = blockIdx.x * 256 + threadIdx.x;
  if (idx < 128 * 128) {
    int n = idx >> 7, k = idx & 127;
    WT[idx] = f2b(W[k * 128 + n]);
  }
}
__global__ void convert_wg(const float* __restrict__ Wg, unsigned short* __restrict__ WgT) {
  int idx = blockIdx.x * 256 + threadIdx.x;
  if (idx < 384 * 384) {
    int n = idx / 384, k = idx - n * 384;
    WgT[idx] = f2b(Wg[k * 384 + n]);
  }
}
__global__ void convert_wa(const float* __restrict__ Wa, unsigned short* __restrict__ WaT) {
  int idx = blockIdx.x * 256 + threadIdx.x;
  if (idx < 128 * 384) {
    int n = idx / 384, k = idx - n * 384;
    WaT[idx] = f2b(Wa[k * 128 + n]);
  }
}

// ---------------------------------------------------------------------------
// Linear: Hb(bf16) = X(fp32) @ W  via MFMA. 64 rows/block, 4 waves x 16 rows.
// ---------------------------------------------------------------------------
#define LM 64
__global__ __launch_bounds__(256) void linear_mfma(
    const float* __restrict__ X, const unsigned short* __restrict__ WT,
    unsigned short* __restrict__ Hb, int nrows) {
  __shared__ unsigned short Xs[LM][136];
  const int t = threadIdx.x;
  const int row0 = blockIdx.x * LM;

  for (int i = t * 4; i < LM * 128; i += 1024) {
    int n = i >> 7, j = i & 127;
    int r = row0 + n;
    float4 v = make_float4(0.f, 0.f, 0.f, 0.f);
    if (r < nrows) v = *(const float4*)&X[(size_t)r * 128 + j];
    Xs[n][j] = f2b(v.x);
    Xs[n][j + 1] = f2b(v.y);
    Xs[n][j + 2] = f2b(v.z);
    Xs[n][j + 3] = f2b(v.w);
  }
  __syncthreads();

  const int wv = t >> 6;
  const int ln = t & 63;
  const int lr = ln & 15;
  const int lq = ln >> 4;
  const int m0 = wv * 16;

  bf16x8 a[4];
#pragma unroll
  for (int ks = 0; ks < 4; ks++)
    a[ks] = *(const bf16x8*)&Xs[m0 + lr][ks * 32 + lq * 8];

#pragma unroll
  for (int np = 0; np < 4; np++) {
    const int n0 = np * 32;
    f32x4 acc0 = {0.f, 0.f, 0.f, 0.f};
    f32x4 acc1 = {0.f, 0.f, 0.f, 0.f};
    const unsigned short* B0 = &WT[(size_t)(n0 + lr) * 128 + lq * 8];
    const unsigned short* B1 = B0 + 16 * 128;
#pragma unroll
    for (int ks = 0; ks < 4; ks++) {
      bf16x8 b0 = *(const bf16x8*)(B0 + ks * 32);
      bf16x8 b1 = *(const bf16x8*)(B1 + ks * 32);
      acc0 = __builtin_amdgcn_mfma_f32_16x16x32_bf16(a[ks], b0, acc0, 0, 0, 0);
      acc1 = __builtin_amdgcn_mfma_f32_16x16x32_bf16(a[ks], b1, acc1, 0, 0, 0);
    }
#pragma unroll
    for (int r = 0; r < 4; r++) {
      int grow = row0 + m0 + lq * 4 + r;
      if (grow < nrows) {
        Hb[(size_t)grow * 128 + n0 + lr] = f2b(acc0[r]);
        Hb[(size_t)grow * 128 + n0 + 16 + lr] = f2b(acc1[r]);
      }
    }
  }
}

// ---------------------------------------------------------------------------
// Partition: 4096 edges/block -> LDS hist -> reserve slack ranges -> LDS-stage
// bucket-ordered -> coalesced flush of (enc, dst) into per-bucket slack region.
// ---------------------------------------------------------------------------
__global__ __launch_bounds__(256) void partition_kernel(
    const int* __restrict__ e1, const int* __restrict__ e2,
    int* __restrict__ bucketCursor, uint2* __restrict__ recs) {
  __shared__ int hist[256];
  __shared__ int scan_s[256];
  __shared__ int lstart[256];
  __shared__ int gbase[NBUCK];
  __shared__ int lcur[NBUCK];
  __shared__ uint2 buf[PCHUNK];  // 32 KB

  const int t = threadIdx.x;
  const long base = (long)blockIdx.x * PCHUNK;
  const int n = (int)min((long)PCHUNK, (long)ETOT - base);

  hist[t] = 0;
  __syncthreads();

  uint2 myrec[PCHUNK / 256];
  int myb[PCHUNK / 256];
  int cnt = 0;
#pragma unroll
  for (int k = 0; k < PCHUNK / 256; k++) {
    int idx = t + k * 256;
    if (idx < n) {
      long i = base + idx;
      int enc, dst;
      if (i < E1) {
        dst = e1[E1 + i];
        enc = N_V + e1[i];
      } else {
        long j = i - E1;
        dst = e2[E2 + j];
        enc = e2[j];
      }
      myrec[cnt] = make_uint2((unsigned)enc, (unsigned)dst);
      int b = dst >> 9;
      myb[cnt] = b;
      atomicAdd(&hist[b], 1);
      cnt++;
    }
  }
  __syncthreads();

  int v = hist[t];
  scan_s[t] = v;
  __syncthreads();
  for (int off = 1; off < 256; off <<= 1) {
    int tmp = (t >= off) ? scan_s[t - off] : 0;
    __syncthreads();
    scan_s[t] += tmp;
    __syncthreads();
  }
  lstart[t] = scan_s[t] - v;
  if (t < NBUCK) {
    gbase[t] = atomicAdd(&bucketCursor[t], v);
    lcur[t] = scan_s[t] - v;
  }
  __syncthreads();

  for (int k = 0; k < cnt; k++) {
    int p = atomicAdd(&lcur[myb[k]], 1);
    buf[p] = myrec[k];
  }
  __syncthreads();

  for (int p = t; p < n; p += 256) {
    uint2 r = buf[p];
    int b = (int)(r.y >> 9);
    recs[(size_t)b * SLACK + gbase[b] + (p - lstart[b])] = r;
  }
}

// Scan bucket counts -> compact bases.
__global__ __launch_bounds__(256) void bucket_scan(
    const int* __restrict__ bucketCnt, int* __restrict__ bucketBase) {
  __shared__ int s[256];
  const int t = threadIdx.x;
  int v = (t < NBUCK) ? bucketCnt[t] : 0;
  s[t] = v;
  __syncthreads();
  for (int off = 1; off < 256; off <<= 1) {
    int tmp = (t >= off) ? s[t - off] : 0;
    __syncthreads();
    s[t] += tmp;
    __syncthreads();
  }
  if (t < NBUCK) bucketBase[t] = s[t] - v;
  if (t == 255) bucketBase[NBUCK] = s[255];
}

// One block per bucket: per-node hist+scan -> row_ptr; two-ended fill so each
// node's segment is [r2 edges ... r1 edges] -> phase-local gathers later.
// col holds BYTE offsets into Hb (enc*256).
__global__ __launch_bounds__(512) void bucket_fill(
    const uint2* __restrict__ recs, const int* __restrict__ bucketCnt,
    const int* __restrict__ bucketBase, int* __restrict__ row_ptr,
    int* __restrict__ col) {
  __shared__ int hist[512];
  __shared__ int s[512];
  __shared__ int curF[512];
  __shared__ int curB[512];
  const int t = threadIdx.x;
  const int b = blockIdx.x;
  const size_t slack = (size_t)b * SLACK;
  const int n = bucketCnt[b];
  const int outBase = bucketBase[b];
  const int n0 = b << 9;

  hist[t] = 0;
  __syncthreads();
  for (int p = t; p < n; p += 512)
    atomicAdd(&hist[recs[slack + p].y - n0], 1);
  __syncthreads();

  int v = hist[t];
  s[t] = v;
  __syncthreads();
  for (int off = 1; off < 512; off <<= 1) {
    int tmp = (t >= off) ? s[t - off] : 0;
    __syncthreads();
    s[t] += tmp;
    __syncthreads();
  }
  int excl = s[t] - v;
  curF[t] = excl;       // front cursor: r2 edges (enc < N_V)
  curB[t] = excl + v;   // back cursor: r1 edges (enc >= N_V)
  int nd = n0 + t;
  if (nd < N_V) row_ptr[nd] = outBase + excl;
  if (b == 0 && t == 0) row_ptr[N_V] = ETOT;
  __syncthreads();

  for (int p = t; p < n; p += 512) {
    uint2 r = recs[slack + p];
    int local = r.y - n0;
    int q;
    if (r.x >= (unsigned)N_V) q = atomicSub(&curB[local], 1) - 1;
    else q = atomicAdd(&curF[local], 1);
    col[outBase + q] = (int)(r.x << 8);  // byte offset of Hb row
  }
}

// ---------------------------------------------------------------------------
// Aggregation over bf16 H: one wave per dst node; lane l holds feats 2l,2l+1.
// col entries are byte offsets; segment ordered r2-then-r1 for L3 phase
// locality (all waves gather from the same 25.6MB half-table at a time).
// ---------------------------------------------------------------------------
__global__ __launch_bounds__(256) void aggregate_kernel(
    const unsigned short* __restrict__ Hb, const int* __restrict__ row_ptr,
    const int* __restrict__ col, unsigned int* __restrict__ SumB,
    unsigned int* __restrict__ MxB) {
  const int node = blockIdx.x * 4 + (threadIdx.x >> 6);
  const int lane = threadIdx.x & 63;
  const int start = row_ptr[node];
  const int end = row_ptr[node + 1];
  const char* Hc = (const char*)Hb;
  const int laneoff = lane * 4;

  float sx = 0.f, sy = 0.f;
  float mx = 0.f, my = 0.f;

  int i = start;
  for (; i + 7 < end; i += 8) {
    unsigned v0 = *(const unsigned*)(Hc + (unsigned)col[i] + laneoff);
    unsigned v1 = *(const unsigned*)(Hc + (unsigned)col[i + 1] + laneoff);
    unsigned v2 = *(const unsigned*)(Hc + (unsigned)col[i + 2] + laneoff);
    unsigned v3 = *(const unsigned*)(Hc + (unsigned)col[i + 3] + laneoff);
    unsigned v4 = *(const unsigned*)(Hc + (unsigned)col[i + 4] + laneoff);
    unsigned v5 = *(const unsigned*)(Hc + (unsigned)col[i + 5] + laneoff);
    unsigned v6 = *(const unsigned*)(Hc + (unsigned)col[i + 6] + laneoff);
    unsigned v7 = *(const unsigned*)(Hc + (unsigned)col[i + 7] + laneoff);
    float x0 = b2f((unsigned short)v0), y0 = b2f((unsigned short)(v0 >> 16));
    float x1 = b2f((unsigned short)v1), y1 = b2f((unsigned short)(v1 >> 16));
    float x2 = b2f((unsigned short)v2), y2 = b2f((unsigned short)(v2 >> 16));
    float x3 = b2f((unsigned short)v3), y3 = b2f((unsigned short)(v3 >> 16));
    float x4 = b2f((unsigned short)v4), y4 = b2f((unsigned short)(v4 >> 16));
    float x5 = b2f((unsigned short)v5), y5 = b2f((unsigned short)(v5 >> 16));
    float x6 = b2f((unsigned short)v6), y6 = b2f((unsigned short)(v6 >> 16));
    float x7 = b2f((unsigned short)v7), y7 = b2f((unsigned short)(v7 >> 16));
    sx += x0; sy += y0; mx = fmaxf(mx, x0); my = fmaxf(my, y0);
    sx += x1; sy += y1; mx = fmaxf(mx, x1); my = fmaxf(my, y1);
    sx += x2; sy += y2; mx = fmaxf(mx, x2); my = fmaxf(my, y2);
    sx += x3; sy += y3; mx = fmaxf(mx, x3); my = fmaxf(my, y3);
    sx += x4; sy += y4; mx = fmaxf(mx, x4); my = fmaxf(my, y4);
    sx += x5; sy += y5; mx = fmaxf(mx, x5); my = fmaxf(my, y5);
    sx += x6; sy += y6; mx = fmaxf(mx, x6); my = fmaxf(my, y6);
    sx += x7; sy += y7; mx = fmaxf(mx, x7); my = fmaxf(my, y7);
  }
  for (; i < end; i++) {
    unsigned v0 = *(const unsigned*)(Hc + (unsigned)col[i] + laneoff);
    float x0 = b2f((unsigned short)v0), y0 = b2f((unsigned short)(v0 >> 16));
    sx += x0; sy += y0; mx = fmaxf(mx, x0); my = fmaxf(my, y0);
  }
  size_t o = (size_t)node * 64 + lane;
  SumB[o] = (unsigned)f2b(sx) | ((unsigned)f2b(sy) << 16);
  MxB[o] = (unsigned)f2b(mx) | ((unsigned)f2b(my) << 16);
}

// ---------------------------------------------------------------------------
// MFMA epilogue v2: B streamed through LDS k-panels (block-shared).
// ---------------------------------------------------------------------------
#define EM 64
__global__ __launch_bounds__(256, 2) void epilogue_mfma(
    const unsigned short* __restrict__ SumB, const unsigned short* __restrict__ MxB,
    const int* __restrict__ row_ptr, const unsigned short* __restrict__ Wg16,
    const float* __restrict__ bg, const unsigned short* __restrict__ Wa16,
    const float* __restrict__ ba, float* __restrict__ Out) {
  __shared__ unsigned short Ts[EM][392];   // 50176 B
  __shared__ unsigned short Bp[384 * 32];  // 24576 B panel
  __shared__ float invs[EM];
  __shared__ int cnts[EM];

  const int t = threadIdx.x;
  const int node0 = blockIdx.x * EM;

  if (t < EM) {
    int nd = node0 + t;
    int c = 0;
    if (nd < N_V) c = row_ptr[nd + 1] - row_ptr[nd];
    cnts[t] = c;
    invs[t] = 1.0f / (float)(c > 0 ? c : 1);
  }
  __syncthreads();

  for (int i = t; i < EM * 128; i += 256) {
    int n = i >> 7, j = i & 127;
    int nd = node0 + n;
    unsigned short sv = 0, mv = 0;
    if (nd < N_V) {
      sv = SumB[(size_t)nd * D + j];
      mv = MxB[(size_t)nd * D + j];
    }
    Ts[n][j] = sv;
    Ts[n][128 + j] = f2b(b2f(sv) * invs[n]);
    Ts[n][256 + j] = mv;
  }

  const int wv = t >> 6;
  const int ln = t & 63;
  const int lr = ln & 15;
  const int lq = ln >> 4;
  const int m0 = wv * 16;

  f32x4 acc[24];
#pragma unroll
  for (int nt = 0; nt < 24; nt++) acc[nt] = (f32x4){0.f, 0.f, 0.f, 0.f};

  for (int kc = 0; kc < 12; kc++) {
    __syncthreads();
    {
      const unsigned short* src = Wg16 + kc * 32;
      for (int i = t; i < 1536; i += 256) {
        int n = i >> 2, part = (i & 3) * 8;
        *(uint4*)&Bp[n * 32 + part] = *(const uint4*)(src + (size_t)n * 384 + part);
      }
    }
    __syncthreads();
    bf16x8 af = *(const bf16x8*)&Ts[m0 + lr][kc * 32 + lq * 8];
#pragma unroll
    for (int nt = 0; nt < 24; nt++) {
      bf16x8 bf = *(const bf16x8*)&Bp[(nt * 16 + lr) * 32 + lq * 8];
      acc[nt] = __builtin_amdgcn_mfma_f32_16x16x32_bf16(af, bf, acc[nt], 0, 0, 0);
    }
  }

#pragma unroll
  for (int nt = 0; nt < 24; nt++) {
    int cg = nt * 16 + lr;
    float bgv = bg[cg];
#pragma unroll
    for (int r = 0; r < 4; r++) {
      int m = m0 + lq * 4 + r;
      float g = 1.f / (1.f + __expf(-(acc[nt][r] + bgv)));
      Ts[m][cg] = f2b(b2f(Ts[m][cg]) * g);
    }
  }

  f32x4 acc2[8];
#pragma unroll
  for (int nt = 0; nt < 8; nt++) acc2[nt] = (f32x4){0.f, 0.f, 0.f, 0.f};

  for (int kc = 0; kc < 12; kc++) {
    __syncthreads();
    {
      const unsigned short* src = Wa16 + kc * 32;
      for (int i = t; i < 512; i += 256) {
        int n = i >> 2, part = (i & 3) * 8;
        *(uint4*)&Bp[n * 32 + part] = *(const uint4*)(src + (size_t)n * 384 + part);
      }
    }
    __syncthreads();
    bf16x8 af = *(const bf16x8*)&Ts[m0 + lr][kc * 32 + lq * 8];
#pragma unroll
    for (int nt = 0; nt < 8; nt++) {
      bf16x8 bf = *(const bf16x8*)&Bp[(nt * 16 + lr) * 32 + lq * 8];
      acc2[nt] = __builtin_amdgcn_mfma_f32_16x16x32_bf16(af, bf, acc2[nt], 0, 0, 0);
    }
  }

#pragma unroll
  for (int nt = 0; nt < 8; nt++) {
    int cg = nt * 16 + lr;
    float bav = ba[cg];
#pragma unroll
    for (int r = 0; r < 4; r++) {
      int m = m0 + lq * 4 + r;
      int nd = node0 + m;
      if (nd < N_V) {
        float msk = (cnts[m] > 0) ? 1.f : 0.f;
        Out[(size_t)nd * D + cg] = (acc2[nt][r] + bav) * msk;
      }
    }
  }
}

// ---------------------------------------------------------------------------
extern "C" void kernel_launch(void* const* d_in, const int* in_sizes, int n_in,
                              void* d_out, int out_size, void* d_ws, size_t ws_size,
                              hipStream_t stream) {
  const float* x_u = (const float*)d_in[0];
  const float* x_v = (const float*)d_in[1];
  const float* W_r1 = (const float*)d_in[2];
  const float* W_r2 = (const float*)d_in[3];
  const float* W_gate = (const float*)d_in[4];
  const float* b_gate = (const float*)d_in[5];
  const float* W_aggr = (const float*)d_in[6];
  const float* b_aggr = (const float*)d_in[7];
  const int* e1 = (const int*)d_in[8];
  const int* e2 = (const int*)d_in[9];
  float* out = (float*)d_out;

  char* ws = (char*)d_ws;
  size_t off = 0;
  unsigned short* Hb = (unsigned short*)(ws + off); off += (size_t)(N_V + N_U) * D * 2;
  unsigned int* SumB = (unsigned int*)(ws + off);   off += (size_t)N_V * D * 2;
  unsigned int* MxB = (unsigned int*)(ws + off);    off += (size_t)N_V * D * 2;
  int* colA = (int*)(ws + off);        off += (size_t)ETOT * 4;
  uint2* recs = (uint2*)(ws + off);    off += (size_t)NBUCK * SLACK * 8;
  int* row_ptr = (int*)(ws + off);     off += (size_t)(N_V + 1) * 4;
  int* bucketCursor = (int*)(ws + off); off += NBUCK * 4;
  int* bucketBase = (int*)(ws + off);  off += (NBUCK + 1) * 4;
  unsigned short* Wg16 = (unsigned short*)(ws + off); off += (size_t)384 * 384 * 2;
  unsigned short* Wa16 = (unsigned short*)(ws + off); off += (size_t)128 * 384 * 2;
  unsigned short* Wr1T = (unsigned short*)(ws + off); off += (size_t)128 * 128 * 2;
  unsigned short* Wr2T = (unsigned short*)(ws + off); off += (size_t)128 * 128 * 2;

  hipMemsetAsync(bucketCursor, 0, NBUCK * 4, stream);

  convert_w128<<<64, 256, 0, stream>>>(W_r1, Wr1T);
  convert_w128<<<64, 256, 0, stream>>>(W_r2, Wr2T);
  convert_wg<<<(384 * 384 + 255) / 256, 256, 0, stream>>>(W_gate, Wg16);
  convert_wa<<<(128 * 384 + 255) / 256, 256, 0, stream>>>(W_aggr, Wa16);

  linear_mfma<<<(N_V + LM - 1) / LM, 256, 0, stream>>>(x_v, Wr2T, Hb, N_V);
  linear_mfma<<<(N_U + LM - 1) / LM, 256, 0, stream>>>(x_u, Wr1T, Hb + (size_t)N_V * D, N_U);

  partition_kernel<<<(ETOT + PCHUNK - 1) / PCHUNK, 256, 0, stream>>>(
      e1, e2, bucketCursor, recs);
  bucket_scan<<<1, 256, 0, stream>>>(bucketCursor, bucketBase);
  bucket_fill<<<NBUCK, 512, 0, stream>>>(recs, bucketCursor, bucketBase, row_ptr, colA);

  aggregate_kernel<<<N_V / 4, 256, 0, stream>>>(Hb, row_ptr, colA, SumB, MxB);

  epilogue_mfma<<<(N_V + EM - 1) / EM, 256, 0, stream>>>(
      (const unsigned short*)SumB, (const unsigned short*)MxB, row_ptr,
      Wg16, b_gate, Wa16, b_aggr, out);
}